// Round 1
// baseline (6011.250 us; speedup 1.0000x reference)
//
#include <hip/hip_runtime.h>

// ---------------------------------------------------------------------------
// GCN forward: proj GEMM -> (GEMM + scatter-agg) x2 -> MLP head + softmax
// All fp32. Round 0: correctness-first baseline with atomic scatter.
// ---------------------------------------------------------------------------

__device__ __forceinline__ void atomAddF(float* p, float v) {
    // HW global_atomic_add_f32 (no CAS loop). Values are normal-range.
    unsafeAtomicAdd(p, v);
}

__device__ __forceinline__ float lane_bcast(float x, int k) {
    return __uint_as_float(__builtin_amdgcn_readlane(__float_as_uint(x), k));
}

// ---------------- degree + dinv ----------------
__global__ void deg_kernel(const int* __restrict__ dst, const float* __restrict__ ew,
                           float* __restrict__ deg, int E) {
    int e = blockIdx.x * blockDim.x + threadIdx.x;
    if (e < E) atomAddF(&deg[dst[e]], ew[e]);
}

__global__ void dinv_kernel(float* __restrict__ deg, int N) {
    int i = blockIdx.x * blockDim.x + threadIdx.x;
    if (i < N) deg[i] = 1.0f / sqrtf(deg[i] + 1.0f);   // deg>=1 always
}

// ---------------- fp32 GEMM: C[M,128] = op(A[M,K]) @ W[K,128] ----------------
// op: optional relu(A + in_bias) on the fly. Optional relu(C + out_bias) on store.
// BM=128, BN=128, BK=16, 256 threads, 8x8 register micro-tile.
template<int K, bool IN_BR, bool OUT_BR>
__global__ __launch_bounds__(256) void gemm_f32(
    const float* __restrict__ A, const float* __restrict__ W,
    const float* __restrict__ in_bias, const float* __restrict__ out_bias,
    float* __restrict__ C, int M)
{
    constexpr int BM = 128, BN = 128, BK = 16;
    __shared__ float As[BK][BM + 4];
    __shared__ float Bs[BK][BN + 4];

    const int tid = threadIdx.x;
    const int tx = tid & 15;        // 0..15 -> col groups
    const int ty = tid >> 4;        // 0..15 -> row groups
    const int m0 = blockIdx.x * BM;

    float acc[8][8];
#pragma unroll
    for (int i = 0; i < 8; i++)
#pragma unroll
        for (int j = 0; j < 8; j++) acc[i][j] = 0.f;

    for (int k0 = 0; k0 < K; k0 += BK) {
        // A tile: 128 rows x 16 cols = 2048 floats; 2 float4 per thread
#pragma unroll
        for (int i = 0; i < 2; i++) {
            int idx = tid + i * 256;          // 0..511
            int row = idx >> 2;               // 0..127
            int kq  = (idx & 3) * 4;          // 0,4,8,12
            int gr  = m0 + row;
            float4 v = make_float4(0.f, 0.f, 0.f, 0.f);
            if (gr < M) v = *reinterpret_cast<const float4*>(&A[(size_t)gr * K + k0 + kq]);
            if (IN_BR) {
                float4 b = *reinterpret_cast<const float4*>(&in_bias[k0 + kq]);
                v.x = fmaxf(v.x + b.x, 0.f);
                v.y = fmaxf(v.y + b.y, 0.f);
                v.z = fmaxf(v.z + b.z, 0.f);
                v.w = fmaxf(v.w + b.w, 0.f);
            }
            As[kq + 0][row] = v.x;
            As[kq + 1][row] = v.y;
            As[kq + 2][row] = v.z;
            As[kq + 3][row] = v.w;
        }
        // B tile: W[k0..k0+16][0..128] = 2048 floats; 2 float4 per thread
#pragma unroll
        for (int i = 0; i < 2; i++) {
            int idx = tid + i * 256;
            int kr  = idx >> 5;               // 0..15
            int nq  = (idx & 31) * 4;         // 0..124
            *reinterpret_cast<float4*>(&Bs[kr][nq]) =
                *reinterpret_cast<const float4*>(&W[(size_t)(k0 + kr) * BN + nq]);
        }
        __syncthreads();

#pragma unroll
        for (int k = 0; k < BK; k++) {
            float4 a0 = *reinterpret_cast<const float4*>(&As[k][ty * 4]);
            float4 a1 = *reinterpret_cast<const float4*>(&As[k][64 + ty * 4]);
            float4 b0 = *reinterpret_cast<const float4*>(&Bs[k][tx * 4]);
            float4 b1 = *reinterpret_cast<const float4*>(&Bs[k][64 + tx * 4]);
            float a[8] = {a0.x, a0.y, a0.z, a0.w, a1.x, a1.y, a1.z, a1.w};
            float b[8] = {b0.x, b0.y, b0.z, b0.w, b1.x, b1.y, b1.z, b1.w};
#pragma unroll
            for (int i = 0; i < 8; i++)
#pragma unroll
                for (int j = 0; j < 8; j++)
                    acc[i][j] = fmaf(a[i], b[j], acc[i][j]);
        }
        __syncthreads();
    }

    // store: rows ty*4..+3 and 64+ty*4..+3; cols tx*4..+3 and 64+tx*4..+3
#pragma unroll
    for (int i = 0; i < 8; i++) {
        int r = m0 + (i < 4 ? ty * 4 + i : 64 + ty * 4 + (i - 4));
        if (r < M) {
            float4 v0 = make_float4(acc[i][0], acc[i][1], acc[i][2], acc[i][3]);
            float4 v1 = make_float4(acc[i][4], acc[i][5], acc[i][6], acc[i][7]);
            if (OUT_BR) {
                float4 c0 = *reinterpret_cast<const float4*>(&out_bias[tx * 4]);
                float4 c1 = *reinterpret_cast<const float4*>(&out_bias[64 + tx * 4]);
                v0.x = fmaxf(v0.x + c0.x, 0.f); v0.y = fmaxf(v0.y + c0.y, 0.f);
                v0.z = fmaxf(v0.z + c0.z, 0.f); v0.w = fmaxf(v0.w + c0.w, 0.f);
                v1.x = fmaxf(v1.x + c1.x, 0.f); v1.y = fmaxf(v1.y + c1.y, 0.f);
                v1.z = fmaxf(v1.z + c1.z, 0.f); v1.w = fmaxf(v1.w + c1.w, 0.f);
            }
            *reinterpret_cast<float4*>(&C[(size_t)r * BN + tx * 4]) = v0;
            *reinterpret_cast<float4*>(&C[(size_t)r * BN + 64 + tx * 4]) = v1;
        }
    }
}

// ---------------- agg init: agg[n] = dinv[n]^2 * hW[n] ----------------
__global__ void init_agg_kernel(const float* __restrict__ dinv, const float* __restrict__ hW,
                                float* __restrict__ agg, int M)
{
    int gid = blockIdx.x * blockDim.x + threadIdx.x;
    int n = gid >> 5;
    int c = (gid & 31) * 4;
    if (n >= M) return;
    float di = dinv[n];
    float s = di * di;
    float4 v = *reinterpret_cast<const float4*>(&hW[(size_t)n * 128 + c]);
    float4 r = make_float4(s * v.x, s * v.y, s * v.z, s * v.w);
    *reinterpret_cast<float4*>(&agg[(size_t)n * 128 + c]) = r;
}

// ---------------- edge scatter: agg[dst] += dinv[s]*ew*dinv[d] * hW[src] ----------------
// 32 threads per edge, float4 per thread -> 4 atomics each.
__global__ void scatter_kernel(const int* __restrict__ src, const int* __restrict__ dst,
                               const float* __restrict__ ew, const float* __restrict__ dinv,
                               const float* __restrict__ hW, float* __restrict__ agg, int E)
{
    int gid = blockIdx.x * blockDim.x + threadIdx.x;
    int e = gid >> 5;
    int c = (gid & 31) * 4;
    if (e >= E) return;
    int s = src[e], d = dst[e];
    float w = dinv[s] * ew[e] * dinv[d];
    float4 v = *reinterpret_cast<const float4*>(&hW[(size_t)s * 128 + c]);
    float* o = &agg[(size_t)d * 128 + c];
    atomAddF(o + 0, w * v.x);
    atomAddF(o + 1, w * v.y);
    atomAddF(o + 2, w * v.z);
    atomAddF(o + 3, w * v.w);
}

// ---------------- fused head: h=relu(agg+b2); a=relu(h@Wl1+bl1);
//                  logits=a@Wl2+bl2; softmax -> out ----------------
// 512 threads (8 waves), Wl1/Wl2 in LDS, 2 nodes per wave per iteration.
__global__ __launch_bounds__(512) void head_kernel(
    const float* __restrict__ h, const float* __restrict__ hbias,
    const float* __restrict__ Wl1, const float* __restrict__ bl1,
    const float* __restrict__ Wl2, const float* __restrict__ bl2,
    float* __restrict__ out, int M)
{
    __shared__ float sW1[128 * 128];
    __shared__ float sW2[128 * 32];
    __shared__ float sb1[128];
    __shared__ float sb2[32];
    __shared__ float sa[8][2][128];

    const int tid = threadIdx.x;
    for (int i = tid * 4; i < 128 * 128; i += 512 * 4)
        *reinterpret_cast<float4*>(&sW1[i]) = *reinterpret_cast<const float4*>(&Wl1[i]);
    for (int i = tid * 4; i < 128 * 32; i += 512 * 4)
        *reinterpret_cast<float4*>(&sW2[i]) = *reinterpret_cast<const float4*>(&Wl2[i]);
    if (tid < 128) sb1[tid] = bl1[tid];
    if (tid >= 128 && tid < 160) sb2[tid - 128] = bl2[tid - 128];
    __syncthreads();

    const int wave = tid >> 6;
    const int lane = tid & 63;
    const int wg = blockIdx.x * 8 + wave;
    const int nw = gridDim.x * 8;
    const int iters = (M + nw * 2 - 1) / (nw * 2);
    const float hb0 = hbias[lane];
    const float hb1 = hbias[64 + lane];

    for (int it = 0; it < iters; it++) {
        const int n0 = 2 * (wg + it * nw);
        const int n1 = n0 + 1;
        const bool v0 = n0 < M, v1 = n1 < M;

        float hA0 = 0.f, hA1 = 0.f, hB0 = 0.f, hB1 = 0.f;
        if (v0) {
            hA0 = fmaxf(h[(size_t)n0 * 128 + lane] + hb0, 0.f);
            hA1 = fmaxf(h[(size_t)n0 * 128 + 64 + lane] + hb1, 0.f);
        }
        if (v1) {
            hB0 = fmaxf(h[(size_t)n1 * 128 + lane] + hb0, 0.f);
            hB1 = fmaxf(h[(size_t)n1 * 128 + 64 + lane] + hb1, 0.f);
        }

        // a[2*lane], a[2*lane+1] for both nodes
        float2 bp2 = *reinterpret_cast<const float2*>(&sb1[2 * lane]);
        float aA0 = bp2.x, aA1 = bp2.y, aB0 = bp2.x, aB1 = bp2.y;
#pragma unroll
        for (int k = 0; k < 64; k++) {
            float2 w = *reinterpret_cast<const float2*>(&sW1[k * 128 + 2 * lane]);
            float ha = lane_bcast(hA0, k);
            float hb = lane_bcast(hB0, k);
            aA0 = fmaf(ha, w.x, aA0); aA1 = fmaf(ha, w.y, aA1);
            aB0 = fmaf(hb, w.x, aB0); aB1 = fmaf(hb, w.y, aB1);
        }
#pragma unroll
        for (int k = 0; k < 64; k++) {
            float2 w = *reinterpret_cast<const float2*>(&sW1[(64 + k) * 128 + 2 * lane]);
            float ha = lane_bcast(hA1, k);
            float hb = lane_bcast(hB1, k);
            aA0 = fmaf(ha, w.x, aA0); aA1 = fmaf(ha, w.y, aA1);
            aB0 = fmaf(hb, w.x, aB0); aB1 = fmaf(hb, w.y, aB1);
        }
        aA0 = fmaxf(aA0, 0.f); aA1 = fmaxf(aA1, 0.f);
        aB0 = fmaxf(aB0, 0.f); aB1 = fmaxf(aB1, 0.f);

        *reinterpret_cast<float2*>(&sa[wave][0][2 * lane]) = make_float2(aA0, aA1);
        *reinterpret_cast<float2*>(&sa[wave][1][2 * lane]) = make_float2(aB0, aB1);
        __syncthreads();

        // logits: lane l -> output o = l&31, k-half kh = l>>5
        const int o = lane & 31;
        const int kh = lane >> 5;
        float pA = 0.f, pB = 0.f;
#pragma unroll
        for (int k = 0; k < 64; k++) {
            int kk = kh * 64 + k;
            float w2 = sW2[kk * 32 + o];
            pA = fmaf(sa[wave][0][kk], w2, pA);
            pB = fmaf(sa[wave][1][kk], w2, pB);
        }
        float lb = sb2[o];
        float lA = pA + __shfl_xor(pA, 32) + lb;
        float lB = pB + __shfl_xor(pB, 32) + lb;

        float mA = lA, mB = lB;
#pragma unroll
        for (int m = 16; m >= 1; m >>= 1) {
            mA = fmaxf(mA, __shfl_xor(mA, m));
            mB = fmaxf(mB, __shfl_xor(mB, m));
        }
        float eA = __expf(lA - mA), eB = __expf(lB - mB);
        float sA = eA, sB = eB;
#pragma unroll
        for (int m = 16; m >= 1; m >>= 1) {
            sA += __shfl_xor(sA, m);
            sB += __shfl_xor(sB, m);
        }
        if (lane < 32) {
            if (v0) out[(size_t)n0 * 32 + o] = eA / sA;
            if (v1) out[(size_t)n1 * 32 + o] = eB / sB;
        }
        __syncthreads();
    }
}

// ---------------------------------------------------------------------------
extern "C" void kernel_launch(void* const* d_in, const int* in_sizes, int n_in,
                              void* d_out, int out_size, void* d_ws, size_t ws_size,
                              hipStream_t stream) {
    const float* x   = (const float*)d_in[0];
    const int*   ei  = (const int*)d_in[1];
    const float* ew  = (const float*)d_in[2];
    const float* Wp  = (const float*)d_in[3];
    const float* bp  = (const float*)d_in[4];
    const float* W1  = (const float*)d_in[5];
    const float* b1  = (const float*)d_in[6];
    const float* W2  = (const float*)d_in[7];
    const float* b2  = (const float*)d_in[8];
    const float* Wl1 = (const float*)d_in[9];
    const float* bl1 = (const float*)d_in[10];
    const float* Wl2 = (const float*)d_in[11];
    const float* bl2 = (const float*)d_in[12];
    float* out = (float*)d_out;

    const int M = in_sizes[0] / 256;   // 100000 nodes
    const int E = in_sizes[2];         // 1600000 edges
    const int* srcp = ei;
    const int* dstp = ei + E;

    char* ws = (char*)d_ws;
    float* dinv = (float*)ws;                                   // M floats
    size_t offA = ((size_t)M * 4 + 255) & ~(size_t)255;
    float* bufA = (float*)(ws + offA);                          // M*128 floats
    float* bufB = bufA + (size_t)M * 128;                       // M*128 floats

    hipMemsetAsync(dinv, 0, (size_t)M * sizeof(float), stream);
    deg_kernel<<<(E + 255) / 256, 256, 0, stream>>>(dstp, ew, dinv, E);
    dinv_kernel<<<(M + 255) / 256, 256, 0, stream>>>(dinv, M);

    const int gblocks = (M + 127) / 128;

    // h0 = relu(x @ Wp + bp)
    gemm_f32<256, false, true><<<gblocks, 256, 0, stream>>>(x, Wp, nullptr, bp, bufA, M);

    // ---- GCN layer 1 ----
    gemm_f32<128, false, false><<<gblocks, 256, 0, stream>>>(bufA, W1, nullptr, nullptr, bufB, M);
    init_agg_kernel<<<(M * 32 + 255) / 256, 256, 0, stream>>>(dinv, bufB, bufA, M);
    scatter_kernel<<<(int)(((size_t)E * 32 + 255) / 256), 256, 0, stream>>>(
        srcp, dstp, ew, dinv, bufB, bufA, E);

    // ---- GCN layer 2 (relu(agg1+b1) fused into GEMM input) ----
    gemm_f32<128, true, false><<<gblocks, 256, 0, stream>>>(bufA, W2, b1, nullptr, bufB, M);
    init_agg_kernel<<<(M * 32 + 255) / 256, 256, 0, stream>>>(dinv, bufB, bufA, M);
    scatter_kernel<<<(int)(((size_t)E * 32 + 255) / 256), 256, 0, stream>>>(
        srcp, dstp, ew, dinv, bufB, bufA, E);

    // ---- head: relu(agg2+b2) -> Wl1/relu -> Wl2 -> softmax ----
    head_kernel<<<512, 512, 0, stream>>>(bufA, b2, Wl1, bl1, Wl2, bl2, out, M);
}

// Round 2
// 1198.225 us; speedup vs baseline: 5.0168x; 5.0168x over previous
//
#include <hip/hip_runtime.h>

// ---------------------------------------------------------------------------
// GCN forward: proj GEMM -> (GEMM + CSR-gather agg) x2 -> MLP head + softmax
// All fp32. Round 1: CSR build (histogram+scan+reorder) replaces atomic
// scatter with a write-once gather. CSR reused across both GCN layers.
// ---------------------------------------------------------------------------

__device__ __forceinline__ void atomAddF(float* p, float v) {
    unsafeAtomicAdd(p, v);   // HW global_atomic_add_f32
}

__device__ __forceinline__ float lane_bcast(float x, int k) {
    return __uint_as_float(__builtin_amdgcn_readlane(__float_as_uint(x), k));
}

// ---------------- degree (weighted, for dinv) + count (for CSR) ----------------
__global__ void deg_cnt_kernel(const int* __restrict__ dst, const float* __restrict__ ew,
                               float* __restrict__ deg, int* __restrict__ cnt, int E) {
    int e = blockIdx.x * blockDim.x + threadIdx.x;
    if (e < E) {
        int d = dst[e];
        atomAddF(&deg[d], ew[e]);
        atomicAdd(&cnt[d], 1);
    }
}

__global__ void dinv_kernel(float* __restrict__ deg, int N) {
    int i = blockIdx.x * blockDim.x + threadIdx.x;
    if (i < N) deg[i] = 1.0f / sqrtf(deg[i] + 1.0f);   // self-loop adds 1
}

// ---------------- single-block exclusive scan: cnt[M] -> rowptr[M+1], cur[M] ----------------
__global__ __launch_bounds__(1024) void scan_kernel(const int* __restrict__ cnt,
                                                    int* __restrict__ rowptr,
                                                    int* __restrict__ cur, int M) {
    __shared__ int part[1024];
    const int tid = threadIdx.x;
    const int chunk = (M + 1023) / 1024;
    const int begin = tid * chunk;
    const int end = min(begin + chunk, M);
    int s = 0;
    for (int i = begin; i < end; i++) s += cnt[i];
    part[tid] = s;
    __syncthreads();
    // Hillis-Steele inclusive scan over 1024 partials
    for (int off = 1; off < 1024; off <<= 1) {
        int v = 0;
        if (tid >= off) v = part[tid - off];
        __syncthreads();
        if (tid >= off) part[tid] += v;
        __syncthreads();
    }
    int run = (tid == 0) ? 0 : part[tid - 1];
    for (int i = begin; i < end; i++) {
        rowptr[i] = run;
        cur[i] = run;
        run += cnt[i];
    }
    if (tid == 0) rowptr[M] = part[1023];
}

// ---------------- reorder edges into CSR buckets: pairs[pos] = (src, norm) ----------------
__global__ void reorder_kernel(const int* __restrict__ src, const int* __restrict__ dst,
                               const float* __restrict__ ew, const float* __restrict__ dinv,
                               int* __restrict__ cur, int2* __restrict__ pairs, int E) {
    int e = blockIdx.x * blockDim.x + threadIdx.x;
    if (e < E) {
        int s = src[e], d = dst[e];
        float w = dinv[s] * ew[e] * dinv[d];
        int pos = atomicAdd(&cur[d], 1);
        pairs[pos] = make_int2(s, __float_as_int(w));
    }
}

// ---------------- CSR gather: agg[n] = dinv[n]^2*hW[n] + sum_e w_e * hW[src_e] ----------------
// One half-wave (32 lanes x float4 = full 128-float row) per node. No atomics.
__global__ __launch_bounds__(256) void gather_kernel(
    const int* __restrict__ rowptr, const int2* __restrict__ pairs,
    const float* __restrict__ dinv, const float* __restrict__ hW,
    float* __restrict__ agg, int M)
{
    int gid = blockIdx.x * blockDim.x + threadIdx.x;
    int n = gid >> 5;
    int c = (gid & 31) * 4;
    if (n >= M) return;
    int beg = rowptr[n], end = rowptr[n + 1];
    float di = dinv[n];
    float s = di * di;
    float4 v = *reinterpret_cast<const float4*>(&hW[(size_t)n * 128 + c]);
    float4 acc = make_float4(s * v.x, s * v.y, s * v.z, s * v.w);
    for (int e = beg; e < end; e++) {
        int2 p = pairs[e];                  // same addr across half-wave -> 1 transaction
        float w = __int_as_float(p.y);
        float4 h = *reinterpret_cast<const float4*>(&hW[(size_t)p.x * 128 + c]);
        acc.x = fmaf(w, h.x, acc.x);
        acc.y = fmaf(w, h.y, acc.y);
        acc.z = fmaf(w, h.z, acc.z);
        acc.w = fmaf(w, h.w, acc.w);
    }
    *reinterpret_cast<float4*>(&agg[(size_t)n * 128 + c]) = acc;
}

// ---------------- fp32 GEMM: C[M,128] = op(A[M,K]) @ W[K,128] ----------------
template<int K, bool IN_BR, bool OUT_BR>
__global__ __launch_bounds__(256) void gemm_f32(
    const float* __restrict__ A, const float* __restrict__ W,
    const float* __restrict__ in_bias, const float* __restrict__ out_bias,
    float* __restrict__ C, int M)
{
    constexpr int BM = 128, BN = 128, BK = 16;
    __shared__ float As[BK][BM + 4];
    __shared__ float Bs[BK][BN + 4];

    const int tid = threadIdx.x;
    const int tx = tid & 15;
    const int ty = tid >> 4;
    const int m0 = blockIdx.x * BM;

    float acc[8][8];
#pragma unroll
    for (int i = 0; i < 8; i++)
#pragma unroll
        for (int j = 0; j < 8; j++) acc[i][j] = 0.f;

    for (int k0 = 0; k0 < K; k0 += BK) {
#pragma unroll
        for (int i = 0; i < 2; i++) {
            int idx = tid + i * 256;
            int row = idx >> 2;
            int kq  = (idx & 3) * 4;
            int gr  = m0 + row;
            float4 v = make_float4(0.f, 0.f, 0.f, 0.f);
            if (gr < M) v = *reinterpret_cast<const float4*>(&A[(size_t)gr * K + k0 + kq]);
            if (IN_BR) {
                float4 b = *reinterpret_cast<const float4*>(&in_bias[k0 + kq]);
                v.x = fmaxf(v.x + b.x, 0.f);
                v.y = fmaxf(v.y + b.y, 0.f);
                v.z = fmaxf(v.z + b.z, 0.f);
                v.w = fmaxf(v.w + b.w, 0.f);
            }
            As[kq + 0][row] = v.x;
            As[kq + 1][row] = v.y;
            As[kq + 2][row] = v.z;
            As[kq + 3][row] = v.w;
        }
#pragma unroll
        for (int i = 0; i < 2; i++) {
            int idx = tid + i * 256;
            int kr  = idx >> 5;
            int nq  = (idx & 31) * 4;
            *reinterpret_cast<float4*>(&Bs[kr][nq]) =
                *reinterpret_cast<const float4*>(&W[(size_t)(k0 + kr) * BN + nq]);
        }
        __syncthreads();

#pragma unroll
        for (int k = 0; k < BK; k++) {
            float4 a0 = *reinterpret_cast<const float4*>(&As[k][ty * 4]);
            float4 a1 = *reinterpret_cast<const float4*>(&As[k][64 + ty * 4]);
            float4 b0 = *reinterpret_cast<const float4*>(&Bs[k][tx * 4]);
            float4 b1 = *reinterpret_cast<const float4*>(&Bs[k][64 + tx * 4]);
            float a[8] = {a0.x, a0.y, a0.z, a0.w, a1.x, a1.y, a1.z, a1.w};
            float b[8] = {b0.x, b0.y, b0.z, b0.w, b1.x, b1.y, b1.z, b1.w};
#pragma unroll
            for (int i = 0; i < 8; i++)
#pragma unroll
                for (int j = 0; j < 8; j++)
                    acc[i][j] = fmaf(a[i], b[j], acc[i][j]);
        }
        __syncthreads();
    }

#pragma unroll
    for (int i = 0; i < 8; i++) {
        int r = m0 + (i < 4 ? ty * 4 + i : 64 + ty * 4 + (i - 4));
        if (r < M) {
            float4 v0 = make_float4(acc[i][0], acc[i][1], acc[i][2], acc[i][3]);
            float4 v1 = make_float4(acc[i][4], acc[i][5], acc[i][6], acc[i][7]);
            if (OUT_BR) {
                float4 c0 = *reinterpret_cast<const float4*>(&out_bias[tx * 4]);
                float4 c1 = *reinterpret_cast<const float4*>(&out_bias[64 + tx * 4]);
                v0.x = fmaxf(v0.x + c0.x, 0.f); v0.y = fmaxf(v0.y + c0.y, 0.f);
                v0.z = fmaxf(v0.z + c0.z, 0.f); v0.w = fmaxf(v0.w + c0.w, 0.f);
                v1.x = fmaxf(v1.x + c1.x, 0.f); v1.y = fmaxf(v1.y + c1.y, 0.f);
                v1.z = fmaxf(v1.z + c1.z, 0.f); v1.w = fmaxf(v1.w + c1.w, 0.f);
            }
            *reinterpret_cast<float4*>(&C[(size_t)r * BN + tx * 4]) = v0;
            *reinterpret_cast<float4*>(&C[(size_t)r * BN + 64 + tx * 4]) = v1;
        }
    }
}

// ---------------- fused head ----------------
__global__ __launch_bounds__(512) void head_kernel(
    const float* __restrict__ h, const float* __restrict__ hbias,
    const float* __restrict__ Wl1, const float* __restrict__ bl1,
    const float* __restrict__ Wl2, const float* __restrict__ bl2,
    float* __restrict__ out, int M)
{
    __shared__ float sW1[128 * 128];
    __shared__ float sW2[128 * 32];
    __shared__ float sb1[128];
    __shared__ float sb2[32];
    __shared__ float sa[8][2][128];

    const int tid = threadIdx.x;
    for (int i = tid * 4; i < 128 * 128; i += 512 * 4)
        *reinterpret_cast<float4*>(&sW1[i]) = *reinterpret_cast<const float4*>(&Wl1[i]);
    for (int i = tid * 4; i < 128 * 32; i += 512 * 4)
        *reinterpret_cast<float4*>(&sW2[i]) = *reinterpret_cast<const float4*>(&Wl2[i]);
    if (tid < 128) sb1[tid] = bl1[tid];
    if (tid >= 128 && tid < 160) sb2[tid - 128] = bl2[tid - 128];
    __syncthreads();

    const int wave = tid >> 6;
    const int lane = tid & 63;
    const int wg = blockIdx.x * 8 + wave;
    const int nw = gridDim.x * 8;
    const int iters = (M + nw * 2 - 1) / (nw * 2);
    const float hb0 = hbias[lane];
    const float hb1 = hbias[64 + lane];

    for (int it = 0; it < iters; it++) {
        const int n0 = 2 * (wg + it * nw);
        const int n1 = n0 + 1;
        const bool v0 = n0 < M, v1 = n1 < M;

        float hA0 = 0.f, hA1 = 0.f, hB0 = 0.f, hB1 = 0.f;
        if (v0) {
            hA0 = fmaxf(h[(size_t)n0 * 128 + lane] + hb0, 0.f);
            hA1 = fmaxf(h[(size_t)n0 * 128 + 64 + lane] + hb1, 0.f);
        }
        if (v1) {
            hB0 = fmaxf(h[(size_t)n1 * 128 + lane] + hb0, 0.f);
            hB1 = fmaxf(h[(size_t)n1 * 128 + 64 + lane] + hb1, 0.f);
        }

        float2 bp2 = *reinterpret_cast<const float2*>(&sb1[2 * lane]);
        float aA0 = bp2.x, aA1 = bp2.y, aB0 = bp2.x, aB1 = bp2.y;
#pragma unroll
        for (int k = 0; k < 64; k++) {
            float2 w = *reinterpret_cast<const float2*>(&sW1[k * 128 + 2 * lane]);
            float ha = lane_bcast(hA0, k);
            float hb = lane_bcast(hB0, k);
            aA0 = fmaf(ha, w.x, aA0); aA1 = fmaf(ha, w.y, aA1);
            aB0 = fmaf(hb, w.x, aB0); aB1 = fmaf(hb, w.y, aB1);
        }
#pragma unroll
        for (int k = 0; k < 64; k++) {
            float2 w = *reinterpret_cast<const float2*>(&sW1[(64 + k) * 128 + 2 * lane]);
            float ha = lane_bcast(hA1, k);
            float hb = lane_bcast(hB1, k);
            aA0 = fmaf(ha, w.x, aA0); aA1 = fmaf(ha, w.y, aA1);
            aB0 = fmaf(hb, w.x, aB0); aB1 = fmaf(hb, w.y, aB1);
        }
        aA0 = fmaxf(aA0, 0.f); aA1 = fmaxf(aA1, 0.f);
        aB0 = fmaxf(aB0, 0.f); aB1 = fmaxf(aB1, 0.f);

        *reinterpret_cast<float2*>(&sa[wave][0][2 * lane]) = make_float2(aA0, aA1);
        *reinterpret_cast<float2*>(&sa[wave][1][2 * lane]) = make_float2(aB0, aB1);
        __syncthreads();

        const int o = lane & 31;
        const int kh = lane >> 5;
        float pA = 0.f, pB = 0.f;
#pragma unroll
        for (int k = 0; k < 64; k++) {
            int kk = kh * 64 + k;
            float w2 = sW2[kk * 32 + o];
            pA = fmaf(sa[wave][0][kk], w2, pA);
            pB = fmaf(sa[wave][1][kk], w2, pB);
        }
        float lb = sb2[o];
        float lA = pA + __shfl_xor(pA, 32) + lb;
        float lB = pB + __shfl_xor(pB, 32) + lb;

        float mA = lA, mB = lB;
#pragma unroll
        for (int m = 16; m >= 1; m >>= 1) {
            mA = fmaxf(mA, __shfl_xor(mA, m));
            mB = fmaxf(mB, __shfl_xor(mB, m));
        }
        float eA = __expf(lA - mA), eB = __expf(lB - mB);
        float sA = eA, sB = eB;
#pragma unroll
        for (int m = 16; m >= 1; m >>= 1) {
            sA += __shfl_xor(sA, m);
            sB += __shfl_xor(sB, m);
        }
        if (lane < 32) {
            if (v0) out[(size_t)n0 * 32 + o] = eA / sA;
            if (v1) out[(size_t)n1 * 32 + o] = eB / sB;
        }
        __syncthreads();
    }
}

// ---------------------------------------------------------------------------
extern "C" void kernel_launch(void* const* d_in, const int* in_sizes, int n_in,
                              void* d_out, int out_size, void* d_ws, size_t ws_size,
                              hipStream_t stream) {
    const float* x   = (const float*)d_in[0];
    const int*   ei  = (const int*)d_in[1];
    const float* ew  = (const float*)d_in[2];
    const float* Wp  = (const float*)d_in[3];
    const float* bp  = (const float*)d_in[4];
    const float* W1  = (const float*)d_in[5];
    const float* b1  = (const float*)d_in[6];
    const float* W2  = (const float*)d_in[7];
    const float* b2  = (const float*)d_in[8];
    const float* Wl1 = (const float*)d_in[9];
    const float* bl1 = (const float*)d_in[10];
    const float* Wl2 = (const float*)d_in[11];
    const float* bl2 = (const float*)d_in[12];
    float* out = (float*)d_out;

    const int M = in_sizes[0] / 256;   // 100000 nodes
    const int E = in_sizes[2];         // 1600000 edges
    const int* srcp = ei;
    const int* dstp = ei + E;

    // ---- workspace layout ----
    char* ws = (char*)d_ws;
    size_t off = 0;
    auto alloc = [&](size_t bytes) { void* p = ws + off; off = (off + bytes + 255) & ~(size_t)255; return p; };
    float* dinv   = (float*)alloc((size_t)M * 4);
    int*   cnt    = (int*)  alloc((size_t)M * 4);
    int*   rowptr = (int*)  alloc((size_t)(M + 1) * 4);
    int*   cur    = (int*)  alloc((size_t)M * 4);
    int2*  pairs  = (int2*) alloc((size_t)E * 8);
    float* bufA   = (float*)alloc((size_t)M * 128 * 4);
    float* bufB   = (float*)alloc((size_t)M * 128 * 4);

    // ---- CSR build (once; reused for both GCN layers) ----
    hipMemsetAsync(dinv, 0, (size_t)M * 4, stream);
    hipMemsetAsync(cnt, 0, (size_t)M * 4, stream);
    deg_cnt_kernel<<<(E + 255) / 256, 256, 0, stream>>>(dstp, ew, dinv, cnt, E);
    dinv_kernel<<<(M + 255) / 256, 256, 0, stream>>>(dinv, M);
    scan_kernel<<<1, 1024, 0, stream>>>(cnt, rowptr, cur, M);
    reorder_kernel<<<(E + 255) / 256, 256, 0, stream>>>(srcp, dstp, ew, dinv, cur, pairs, E);

    const int gblocks = (M + 127) / 128;
    const int hblocks = (int)(((size_t)M * 32 + 255) / 256);

    // h0 = relu(x @ Wp + bp)
    gemm_f32<256, false, true><<<gblocks, 256, 0, stream>>>(x, Wp, nullptr, bp, bufA, M);

    // ---- GCN layer 1 ----
    gemm_f32<128, false, false><<<gblocks, 256, 0, stream>>>(bufA, W1, nullptr, nullptr, bufB, M);
    gather_kernel<<<hblocks, 256, 0, stream>>>(rowptr, pairs, dinv, bufB, bufA, M);

    // ---- GCN layer 2 (relu(agg1+b1) fused into GEMM input) ----
    gemm_f32<128, true, false><<<gblocks, 256, 0, stream>>>(bufA, W2, b1, nullptr, bufB, M);
    gather_kernel<<<hblocks, 256, 0, stream>>>(rowptr, pairs, dinv, bufB, bufA, M);

    // ---- head ----
    head_kernel<<<512, 512, 0, stream>>>(bufA, b2, Wl1, bl1, Wl2, bl2, out, M);
}

// Round 3
// 986.332 us; speedup vs baseline: 6.0945x; 1.2148x over previous
//
#include <hip/hip_runtime.h>

// ---------------------------------------------------------------------------
// GCN forward: proj GEMM -> (GEMM + CSR-gather agg) x2 -> MLP head + softmax
// All fp32. Round 2: hierarchical 3-kernel scan replaces the single-block
// scan (was 231 us at 0.15% occupancy -> ~15 us total).
// ---------------------------------------------------------------------------

__device__ __forceinline__ void atomAddF(float* p, float v) {
    unsafeAtomicAdd(p, v);   // HW global_atomic_add_f32
}

__device__ __forceinline__ float lane_bcast(float x, int k) {
    return __uint_as_float(__builtin_amdgcn_readlane(__float_as_uint(x), k));
}

// ---------------- degree (weighted, for dinv) + count (for CSR) ----------------
__global__ void deg_cnt_kernel(const int* __restrict__ dst, const float* __restrict__ ew,
                               float* __restrict__ deg, int* __restrict__ cnt, int E) {
    int e = blockIdx.x * blockDim.x + threadIdx.x;
    if (e < E) {
        int d = dst[e];
        atomAddF(&deg[d], ew[e]);
        atomicAdd(&cnt[d], 1);
    }
}

__global__ void dinv_kernel(float* __restrict__ deg, int N) {
    int i = blockIdx.x * blockDim.x + threadIdx.x;
    if (i < N) deg[i] = 1.0f / sqrtf(deg[i] + 1.0f);   // self-loop adds 1
}

// ---------------- hierarchical exclusive scan: cnt[M] -> rowptr[M+1], cur[M] ----
// TILE = 2048 elements per 256-thread block (8 per thread).
__global__ __launch_bounds__(256) void scan_reduce(const int* __restrict__ cnt,
                                                   int* __restrict__ bsum, int M) {
    __shared__ int wsum[4];
    const int t = threadIdx.x;
    const int base = blockIdx.x * 2048 + t * 8;
    int s = 0;
#pragma unroll
    for (int j = 0; j < 8; j++) {
        int i = base + j;
        if (i < M) s += cnt[i];
    }
#pragma unroll
    for (int off = 1; off < 64; off <<= 1) s += __shfl_xor(s, off);
    if ((t & 63) == 0) wsum[t >> 6] = s;
    __syncthreads();
    if (t == 0) bsum[blockIdx.x] = wsum[0] + wsum[1] + wsum[2] + wsum[3];
}

// single wave scans the block sums (nb <= 64*chunk), writes exclusive offsets
__global__ void scan_bsum(int* __restrict__ bsum, int* __restrict__ rowptr_last, int nb) {
    const int lane = threadIdx.x;   // 64 lanes
    const int chunk = (nb + 63) / 64;
    const int b0 = lane * chunk;
    const int b1 = min(b0 + chunk, nb);
    int s = 0;
    for (int i = b0; i < b1; i++) s += bsum[i];
    int inc = s;
#pragma unroll
    for (int off = 1; off < 64; off <<= 1) {
        int u = __shfl_up(inc, off);
        if (lane >= off) inc += u;
    }
    int run = inc - s;   // exclusive prefix of this lane's chunk
    for (int i = b0; i < b1; i++) {
        int v = bsum[i];
        bsum[i] = run;
        run += v;
    }
    if (lane == 63) *rowptr_last = inc;   // total = E
}

__global__ __launch_bounds__(256) void scan_down(const int* __restrict__ cnt,
                                                 const int* __restrict__ bsum,
                                                 int* __restrict__ rowptr,
                                                 int* __restrict__ cur, int M) {
    __shared__ int wpre[4];
    const int t = threadIdx.x;
    const int lane = t & 63;
    const int w = t >> 6;
    const int base = blockIdx.x * 2048 + t * 8;
    int c[8];
    int s = 0;
#pragma unroll
    for (int j = 0; j < 8; j++) {
        int i = base + j;
        c[j] = (i < M) ? cnt[i] : 0;
        s += c[j];
    }
    int inc = s;
#pragma unroll
    for (int off = 1; off < 64; off <<= 1) {
        int u = __shfl_up(inc, off);
        if (lane >= off) inc += u;
    }
    if (lane == 63) wpre[w] = inc;
    __syncthreads();
    int woff = 0;
#pragma unroll
    for (int i = 0; i < 4; i++)
        if (i < w) woff += wpre[i];
    int run = bsum[blockIdx.x] + woff + (inc - s);
#pragma unroll
    for (int j = 0; j < 8; j++) {
        int i = base + j;
        if (i < M) {
            rowptr[i] = run;
            cur[i] = run;
            run += c[j];
        }
    }
}

// ---------------- reorder edges into CSR buckets: pairs[pos] = (src, norm) ----------------
__global__ void reorder_kernel(const int* __restrict__ src, const int* __restrict__ dst,
                               const float* __restrict__ ew, const float* __restrict__ dinv,
                               int* __restrict__ cur, int2* __restrict__ pairs, int E) {
    int e = blockIdx.x * blockDim.x + threadIdx.x;
    if (e < E) {
        int s = src[e], d = dst[e];
        float w = dinv[s] * ew[e] * dinv[d];
        int pos = atomicAdd(&cur[d], 1);
        pairs[pos] = make_int2(s, __float_as_int(w));
    }
}

// ---------------- CSR gather: agg[n] = dinv[n]^2*hW[n] + sum_e w_e * hW[src_e] ----------------
__global__ __launch_bounds__(256) void gather_kernel(
    const int* __restrict__ rowptr, const int2* __restrict__ pairs,
    const float* __restrict__ dinv, const float* __restrict__ hW,
    float* __restrict__ agg, int M)
{
    int gid = blockIdx.x * blockDim.x + threadIdx.x;
    int n = gid >> 5;
    int c = (gid & 31) * 4;
    if (n >= M) return;
    int beg = rowptr[n], end = rowptr[n + 1];
    float di = dinv[n];
    float s = di * di;
    float4 v = *reinterpret_cast<const float4*>(&hW[(size_t)n * 128 + c]);
    float4 acc = make_float4(s * v.x, s * v.y, s * v.z, s * v.w);
    for (int e = beg; e < end; e++) {
        int2 p = pairs[e];
        float w = __int_as_float(p.y);
        float4 h = *reinterpret_cast<const float4*>(&hW[(size_t)p.x * 128 + c]);
        acc.x = fmaf(w, h.x, acc.x);
        acc.y = fmaf(w, h.y, acc.y);
        acc.z = fmaf(w, h.z, acc.z);
        acc.w = fmaf(w, h.w, acc.w);
    }
    *reinterpret_cast<float4*>(&agg[(size_t)n * 128 + c]) = acc;
}

// ---------------- fp32 GEMM: C[M,128] = op(A[M,K]) @ W[K,128] ----------------
template<int K, bool IN_BR, bool OUT_BR>
__global__ __launch_bounds__(256) void gemm_f32(
    const float* __restrict__ A, const float* __restrict__ W,
    const float* __restrict__ in_bias, const float* __restrict__ out_bias,
    float* __restrict__ C, int M)
{
    constexpr int BM = 128, BN = 128, BK = 16;
    __shared__ float As[BK][BM + 4];
    __shared__ float Bs[BK][BN + 4];

    const int tid = threadIdx.x;
    const int tx = tid & 15;
    const int ty = tid >> 4;
    const int m0 = blockIdx.x * BM;

    float acc[8][8];
#pragma unroll
    for (int i = 0; i < 8; i++)
#pragma unroll
        for (int j = 0; j < 8; j++) acc[i][j] = 0.f;

    for (int k0 = 0; k0 < K; k0 += BK) {
#pragma unroll
        for (int i = 0; i < 2; i++) {
            int idx = tid + i * 256;
            int row = idx >> 2;
            int kq  = (idx & 3) * 4;
            int gr  = m0 + row;
            float4 v = make_float4(0.f, 0.f, 0.f, 0.f);
            if (gr < M) v = *reinterpret_cast<const float4*>(&A[(size_t)gr * K + k0 + kq]);
            if (IN_BR) {
                float4 b = *reinterpret_cast<const float4*>(&in_bias[k0 + kq]);
                v.x = fmaxf(v.x + b.x, 0.f);
                v.y = fmaxf(v.y + b.y, 0.f);
                v.z = fmaxf(v.z + b.z, 0.f);
                v.w = fmaxf(v.w + b.w, 0.f);
            }
            As[kq + 0][row] = v.x;
            As[kq + 1][row] = v.y;
            As[kq + 2][row] = v.z;
            As[kq + 3][row] = v.w;
        }
#pragma unroll
        for (int i = 0; i < 2; i++) {
            int idx = tid + i * 256;
            int kr  = idx >> 5;
            int nq  = (idx & 31) * 4;
            *reinterpret_cast<float4*>(&Bs[kr][nq]) =
                *reinterpret_cast<const float4*>(&W[(size_t)(k0 + kr) * BN + nq]);
        }
        __syncthreads();

#pragma unroll
        for (int k = 0; k < BK; k++) {
            float4 a0 = *reinterpret_cast<const float4*>(&As[k][ty * 4]);
            float4 a1 = *reinterpret_cast<const float4*>(&As[k][64 + ty * 4]);
            float4 b0 = *reinterpret_cast<const float4*>(&Bs[k][tx * 4]);
            float4 b1 = *reinterpret_cast<const float4*>(&Bs[k][64 + tx * 4]);
            float a[8] = {a0.x, a0.y, a0.z, a0.w, a1.x, a1.y, a1.z, a1.w};
            float b[8] = {b0.x, b0.y, b0.z, b0.w, b1.x, b1.y, b1.z, b1.w};
#pragma unroll
            for (int i = 0; i < 8; i++)
#pragma unroll
                for (int j = 0; j < 8; j++)
                    acc[i][j] = fmaf(a[i], b[j], acc[i][j]);
        }
        __syncthreads();
    }

#pragma unroll
    for (int i = 0; i < 8; i++) {
        int r = m0 + (i < 4 ? ty * 4 + i : 64 + ty * 4 + (i - 4));
        if (r < M) {
            float4 v0 = make_float4(acc[i][0], acc[i][1], acc[i][2], acc[i][3]);
            float4 v1 = make_float4(acc[i][4], acc[i][5], acc[i][6], acc[i][7]);
            if (OUT_BR) {
                float4 c0 = *reinterpret_cast<const float4*>(&out_bias[tx * 4]);
                float4 c1 = *reinterpret_cast<const float4*>(&out_bias[64 + tx * 4]);
                v0.x = fmaxf(v0.x + c0.x, 0.f); v0.y = fmaxf(v0.y + c0.y, 0.f);
                v0.z = fmaxf(v0.z + c0.z, 0.f); v0.w = fmaxf(v0.w + c0.w, 0.f);
                v1.x = fmaxf(v1.x + c1.x, 0.f); v1.y = fmaxf(v1.y + c1.y, 0.f);
                v1.z = fmaxf(v1.z + c1.z, 0.f); v1.w = fmaxf(v1.w + c1.w, 0.f);
            }
            *reinterpret_cast<float4*>(&C[(size_t)r * BN + tx * 4]) = v0;
            *reinterpret_cast<float4*>(&C[(size_t)r * BN + 64 + tx * 4]) = v1;
        }
    }
}

// ---------------- fused head ----------------
__global__ __launch_bounds__(512) void head_kernel(
    const float* __restrict__ h, const float* __restrict__ hbias,
    const float* __restrict__ Wl1, const float* __restrict__ bl1,
    const float* __restrict__ Wl2, const float* __restrict__ bl2,
    float* __restrict__ out, int M)
{
    __shared__ float sW1[128 * 128];
    __shared__ float sW2[128 * 32];
    __shared__ float sb1[128];
    __shared__ float sb2[32];
    __shared__ float sa[8][2][128];

    const int tid = threadIdx.x;
    for (int i = tid * 4; i < 128 * 128; i += 512 * 4)
        *reinterpret_cast<float4*>(&sW1[i]) = *reinterpret_cast<const float4*>(&Wl1[i]);
    for (int i = tid * 4; i < 128 * 32; i += 512 * 4)
        *reinterpret_cast<float4*>(&sW2[i]) = *reinterpret_cast<const float4*>(&Wl2[i]);
    if (tid < 128) sb1[tid] = bl1[tid];
    if (tid >= 128 && tid < 160) sb2[tid - 128] = bl2[tid - 128];
    __syncthreads();

    const int wave = tid >> 6;
    const int lane = tid & 63;
    const int wg = blockIdx.x * 8 + wave;
    const int nw = gridDim.x * 8;
    const int iters = (M + nw * 2 - 1) / (nw * 2);
    const float hb0 = hbias[lane];
    const float hb1 = hbias[64 + lane];

    for (int it = 0; it < iters; it++) {
        const int n0 = 2 * (wg + it * nw);
        const int n1 = n0 + 1;
        const bool v0 = n0 < M, v1 = n1 < M;

        float hA0 = 0.f, hA1 = 0.f, hB0 = 0.f, hB1 = 0.f;
        if (v0) {
            hA0 = fmaxf(h[(size_t)n0 * 128 + lane] + hb0, 0.f);
            hA1 = fmaxf(h[(size_t)n0 * 128 + 64 + lane] + hb1, 0.f);
        }
        if (v1) {
            hB0 = fmaxf(h[(size_t)n1 * 128 + lane] + hb0, 0.f);
            hB1 = fmaxf(h[(size_t)n1 * 128 + 64 + lane] + hb1, 0.f);
        }

        float2 bp2 = *reinterpret_cast<const float2*>(&sb1[2 * lane]);
        float aA0 = bp2.x, aA1 = bp2.y, aB0 = bp2.x, aB1 = bp2.y;
#pragma unroll
        for (int k = 0; k < 64; k++) {
            float2 w = *reinterpret_cast<const float2*>(&sW1[k * 128 + 2 * lane]);
            float ha = lane_bcast(hA0, k);
            float hb = lane_bcast(hB0, k);
            aA0 = fmaf(ha, w.x, aA0); aA1 = fmaf(ha, w.y, aA1);
            aB0 = fmaf(hb, w.x, aB0); aB1 = fmaf(hb, w.y, aB1);
        }
#pragma unroll
        for (int k = 0; k < 64; k++) {
            float2 w = *reinterpret_cast<const float2*>(&sW1[(64 + k) * 128 + 2 * lane]);
            float ha = lane_bcast(hA1, k);
            float hb = lane_bcast(hB1, k);
            aA0 = fmaf(ha, w.x, aA0); aA1 = fmaf(ha, w.y, aA1);
            aB0 = fmaf(hb, w.x, aB0); aB1 = fmaf(hb, w.y, aB1);
        }
        aA0 = fmaxf(aA0, 0.f); aA1 = fmaxf(aA1, 0.f);
        aB0 = fmaxf(aB0, 0.f); aB1 = fmaxf(aB1, 0.f);

        *reinterpret_cast<float2*>(&sa[wave][0][2 * lane]) = make_float2(aA0, aA1);
        *reinterpret_cast<float2*>(&sa[wave][1][2 * lane]) = make_float2(aB0, aB1);
        __syncthreads();

        const int o = lane & 31;
        const int kh = lane >> 5;
        float pA = 0.f, pB = 0.f;
#pragma unroll
        for (int k = 0; k < 64; k++) {
            int kk = kh * 64 + k;
            float w2 = sW2[kk * 32 + o];
            pA = fmaf(sa[wave][0][kk], w2, pA);
            pB = fmaf(sa[wave][1][kk], w2, pB);
        }
        float lb = sb2[o];
        float lA = pA + __shfl_xor(pA, 32) + lb;
        float lB = pB + __shfl_xor(pB, 32) + lb;

        float mA = lA, mB = lB;
#pragma unroll
        for (int m = 16; m >= 1; m >>= 1) {
            mA = fmaxf(mA, __shfl_xor(mA, m));
            mB = fmaxf(mB, __shfl_xor(mB, m));
        }
        float eA = __expf(lA - mA), eB = __expf(lB - mB);
        float sA = eA, sB = eB;
#pragma unroll
        for (int m = 16; m >= 1; m >>= 1) {
            sA += __shfl_xor(sA, m);
            sB += __shfl_xor(sB, m);
        }
        if (lane < 32) {
            if (v0) out[(size_t)n0 * 32 + o] = eA / sA;
            if (v1) out[(size_t)n1 * 32 + o] = eB / sB;
        }
        __syncthreads();
    }
}

// ---------------------------------------------------------------------------
extern "C" void kernel_launch(void* const* d_in, const int* in_sizes, int n_in,
                              void* d_out, int out_size, void* d_ws, size_t ws_size,
                              hipStream_t stream) {
    const float* x   = (const float*)d_in[0];
    const int*   ei  = (const int*)d_in[1];
    const float* ew  = (const float*)d_in[2];
    const float* Wp  = (const float*)d_in[3];
    const float* bp  = (const float*)d_in[4];
    const float* W1  = (const float*)d_in[5];
    const float* b1  = (const float*)d_in[6];
    const float* W2  = (const float*)d_in[7];
    const float* b2  = (const float*)d_in[8];
    const float* Wl1 = (const float*)d_in[9];
    const float* bl1 = (const float*)d_in[10];
    const float* Wl2 = (const float*)d_in[11];
    const float* bl2 = (const float*)d_in[12];
    float* out = (float*)d_out;

    const int M = in_sizes[0] / 256;   // 100000 nodes
    const int E = in_sizes[2];         // 1600000 edges
    const int* srcp = ei;
    const int* dstp = ei + E;

    // ---- workspace layout ----
    char* ws = (char*)d_ws;
    size_t off = 0;
    auto alloc = [&](size_t bytes) { void* p = ws + off; off = (off + bytes + 255) & ~(size_t)255; return p; };
    float* dinv   = (float*)alloc((size_t)M * 4);
    int*   cnt    = (int*)  alloc((size_t)M * 4);
    int*   rowptr = (int*)  alloc((size_t)(M + 1) * 4);
    int*   cur    = (int*)  alloc((size_t)M * 4);
    int*   bsum   = (int*)  alloc((size_t)4096 * 4);
    int2*  pairs  = (int2*) alloc((size_t)E * 8);
    float* bufA   = (float*)alloc((size_t)M * 128 * 4);
    float* bufB   = (float*)alloc((size_t)M * 128 * 4);

    const int ntiles = (M + 2047) / 2048;

    // ---- CSR build (once; reused for both GCN layers) ----
    hipMemsetAsync(dinv, 0, (size_t)M * 4, stream);
    hipMemsetAsync(cnt, 0, (size_t)M * 4, stream);
    deg_cnt_kernel<<<(E + 255) / 256, 256, 0, stream>>>(dstp, ew, dinv, cnt, E);
    dinv_kernel<<<(M + 255) / 256, 256, 0, stream>>>(dinv, M);
    scan_reduce<<<ntiles, 256, 0, stream>>>(cnt, bsum, M);
    scan_bsum<<<1, 64, 0, stream>>>(bsum, rowptr + M, ntiles);
    scan_down<<<ntiles, 256, 0, stream>>>(cnt, bsum, rowptr, cur, M);
    reorder_kernel<<<(E + 255) / 256, 256, 0, stream>>>(srcp, dstp, ew, dinv, cur, pairs, E);

    const int gblocks = (M + 127) / 128;
    const int hblocks = (int)(((size_t)M * 32 + 255) / 256);

    // h0 = relu(x @ Wp + bp)
    gemm_f32<256, false, true><<<gblocks, 256, 0, stream>>>(x, Wp, nullptr, bp, bufA, M);

    // ---- GCN layer 1 ----
    gemm_f32<128, false, false><<<gblocks, 256, 0, stream>>>(bufA, W1, nullptr, nullptr, bufB, M);
    gather_kernel<<<hblocks, 256, 0, stream>>>(rowptr, pairs, dinv, bufB, bufA, M);

    // ---- GCN layer 2 (relu(agg1+b1) fused into GEMM input) ----
    gemm_f32<128, true, false><<<gblocks, 256, 0, stream>>>(bufA, W2, b1, nullptr, bufB, M);
    gather_kernel<<<hblocks, 256, 0, stream>>>(rowptr, pairs, dinv, bufB, bufA, M);

    // ---- head ----
    head_kernel<<<512, 512, 0, stream>>>(bufA, b2, Wl1, bl1, Wl2, bl2, out, M);
}

// Round 4
// 956.675 us; speedup vs baseline: 6.2835x; 1.0310x over previous
//
#include <hip/hip_runtime.h>

// ---------------------------------------------------------------------------
// GCN forward: proj GEMM -> (GEMM + CSR-gather agg) x2 -> head GEMM ->
// logits+softmax. All fp32.
// Round 3: head_kernel split into gemm_f32 + logits_kernel; gather unrolled
// x4 with dual accumulators for memory-level parallelism.
// ---------------------------------------------------------------------------

__device__ __forceinline__ void atomAddF(float* p, float v) {
    unsafeAtomicAdd(p, v);   // HW global_atomic_add_f32
}

// ---------------- degree (weighted, for dinv) + count (for CSR) ----------------
__global__ void deg_cnt_kernel(const int* __restrict__ dst, const float* __restrict__ ew,
                               float* __restrict__ deg, int* __restrict__ cnt, int E) {
    int e = blockIdx.x * blockDim.x + threadIdx.x;
    if (e < E) {
        int d = dst[e];
        atomAddF(&deg[d], ew[e]);
        atomicAdd(&cnt[d], 1);
    }
}

__global__ void dinv_kernel(float* __restrict__ deg, int N) {
    int i = blockIdx.x * blockDim.x + threadIdx.x;
    if (i < N) deg[i] = 1.0f / sqrtf(deg[i] + 1.0f);   // self-loop adds 1
}

// ---------------- hierarchical exclusive scan: cnt[M] -> rowptr[M+1], cur[M] ----
__global__ __launch_bounds__(256) void scan_reduce(const int* __restrict__ cnt,
                                                   int* __restrict__ bsum, int M) {
    __shared__ int wsum[4];
    const int t = threadIdx.x;
    const int base = blockIdx.x * 2048 + t * 8;
    int s = 0;
#pragma unroll
    for (int j = 0; j < 8; j++) {
        int i = base + j;
        if (i < M) s += cnt[i];
    }
#pragma unroll
    for (int off = 1; off < 64; off <<= 1) s += __shfl_xor(s, off);
    if ((t & 63) == 0) wsum[t >> 6] = s;
    __syncthreads();
    if (t == 0) bsum[blockIdx.x] = wsum[0] + wsum[1] + wsum[2] + wsum[3];
}

__global__ void scan_bsum(int* __restrict__ bsum, int* __restrict__ rowptr_last, int nb) {
    const int lane = threadIdx.x;   // 64 lanes
    const int chunk = (nb + 63) / 64;
    const int b0 = lane * chunk;
    const int b1 = min(b0 + chunk, nb);
    int s = 0;
    for (int i = b0; i < b1; i++) s += bsum[i];
    int inc = s;
#pragma unroll
    for (int off = 1; off < 64; off <<= 1) {
        int u = __shfl_up(inc, off);
        if (lane >= off) inc += u;
    }
    int run = inc - s;
    for (int i = b0; i < b1; i++) {
        int v = bsum[i];
        bsum[i] = run;
        run += v;
    }
    if (lane == 63) *rowptr_last = inc;   // total = E
}

__global__ __launch_bounds__(256) void scan_down(const int* __restrict__ cnt,
                                                 const int* __restrict__ bsum,
                                                 int* __restrict__ rowptr,
                                                 int* __restrict__ cur, int M) {
    __shared__ int wpre[4];
    const int t = threadIdx.x;
    const int lane = t & 63;
    const int w = t >> 6;
    const int base = blockIdx.x * 2048 + t * 8;
    int c[8];
    int s = 0;
#pragma unroll
    for (int j = 0; j < 8; j++) {
        int i = base + j;
        c[j] = (i < M) ? cnt[i] : 0;
        s += c[j];
    }
    int inc = s;
#pragma unroll
    for (int off = 1; off < 64; off <<= 1) {
        int u = __shfl_up(inc, off);
        if (lane >= off) inc += u;
    }
    if (lane == 63) wpre[w] = inc;
    __syncthreads();
    int woff = 0;
#pragma unroll
    for (int i = 0; i < 4; i++)
        if (i < w) woff += wpre[i];
    int run = bsum[blockIdx.x] + woff + (inc - s);
#pragma unroll
    for (int j = 0; j < 8; j++) {
        int i = base + j;
        if (i < M) {
            rowptr[i] = run;
            cur[i] = run;
            run += c[j];
        }
    }
}

// ---------------- reorder edges into CSR buckets: pairs[pos] = (src, norm) ----------------
__global__ void reorder_kernel(const int* __restrict__ src, const int* __restrict__ dst,
                               const float* __restrict__ ew, const float* __restrict__ dinv,
                               int* __restrict__ cur, int2* __restrict__ pairs, int E) {
    int e = blockIdx.x * blockDim.x + threadIdx.x;
    if (e < E) {
        int s = src[e], d = dst[e];
        float w = dinv[s] * ew[e] * dinv[d];
        int pos = atomicAdd(&cur[d], 1);
        pairs[pos] = make_int2(s, __float_as_int(w));
    }
}

// ---------------- CSR gather: agg[n] = dinv[n]^2*hW[n] + sum_e w_e * hW[src_e] ----------------
// One half-wave (32 lanes x float4 = full 128-float row) per node. Unroll x4,
// dual accumulators -> 4 row loads in flight.
__global__ __launch_bounds__(256) void gather_kernel(
    const int* __restrict__ rowptr, const int2* __restrict__ pairs,
    const float* __restrict__ dinv, const float* __restrict__ hW,
    float* __restrict__ agg, int M)
{
    int gid = blockIdx.x * blockDim.x + threadIdx.x;
    int n = gid >> 5;
    int c = (gid & 31) * 4;
    if (n >= M) return;
    int beg = rowptr[n], end = rowptr[n + 1];
    float di = dinv[n];
    float s = di * di;
    float4 v = *reinterpret_cast<const float4*>(&hW[(size_t)n * 128 + c]);
    float4 acc0 = make_float4(s * v.x, s * v.y, s * v.z, s * v.w);
    float4 acc1 = make_float4(0.f, 0.f, 0.f, 0.f);

    int e = beg;
    for (; e + 4 <= end; e += 4) {
        int2 p0 = pairs[e + 0];
        int2 p1 = pairs[e + 1];
        int2 p2 = pairs[e + 2];
        int2 p3 = pairs[e + 3];
        float4 h0 = *reinterpret_cast<const float4*>(&hW[(size_t)p0.x * 128 + c]);
        float4 h1 = *reinterpret_cast<const float4*>(&hW[(size_t)p1.x * 128 + c]);
        float4 h2 = *reinterpret_cast<const float4*>(&hW[(size_t)p2.x * 128 + c]);
        float4 h3 = *reinterpret_cast<const float4*>(&hW[(size_t)p3.x * 128 + c]);
        float w0 = __int_as_float(p0.y), w1 = __int_as_float(p1.y);
        float w2 = __int_as_float(p2.y), w3 = __int_as_float(p3.y);
        acc0.x = fmaf(w0, h0.x, acc0.x); acc0.y = fmaf(w0, h0.y, acc0.y);
        acc0.z = fmaf(w0, h0.z, acc0.z); acc0.w = fmaf(w0, h0.w, acc0.w);
        acc1.x = fmaf(w1, h1.x, acc1.x); acc1.y = fmaf(w1, h1.y, acc1.y);
        acc1.z = fmaf(w1, h1.z, acc1.z); acc1.w = fmaf(w1, h1.w, acc1.w);
        acc0.x = fmaf(w2, h2.x, acc0.x); acc0.y = fmaf(w2, h2.y, acc0.y);
        acc0.z = fmaf(w2, h2.z, acc0.z); acc0.w = fmaf(w2, h2.w, acc0.w);
        acc1.x = fmaf(w3, h3.x, acc1.x); acc1.y = fmaf(w3, h3.y, acc1.y);
        acc1.z = fmaf(w3, h3.z, acc1.z); acc1.w = fmaf(w3, h3.w, acc1.w);
    }
    for (; e < end; e++) {
        int2 p = pairs[e];
        float w = __int_as_float(p.y);
        float4 h = *reinterpret_cast<const float4*>(&hW[(size_t)p.x * 128 + c]);
        acc0.x = fmaf(w, h.x, acc0.x);
        acc0.y = fmaf(w, h.y, acc0.y);
        acc0.z = fmaf(w, h.z, acc0.z);
        acc0.w = fmaf(w, h.w, acc0.w);
    }
    acc0.x += acc1.x; acc0.y += acc1.y; acc0.z += acc1.z; acc0.w += acc1.w;
    *reinterpret_cast<float4*>(&agg[(size_t)n * 128 + c]) = acc0;
}

// ---------------- fp32 GEMM: C[M,128] = op(A[M,K]) @ W[K,128] ----------------
template<int K, bool IN_BR, bool OUT_BR>
__global__ __launch_bounds__(256) void gemm_f32(
    const float* __restrict__ A, const float* __restrict__ W,
    const float* __restrict__ in_bias, const float* __restrict__ out_bias,
    float* __restrict__ C, int M)
{
    constexpr int BM = 128, BN = 128, BK = 16;
    __shared__ float As[BK][BM + 4];
    __shared__ float Bs[BK][BN + 4];

    const int tid = threadIdx.x;
    const int tx = tid & 15;
    const int ty = tid >> 4;
    const int m0 = blockIdx.x * BM;

    float acc[8][8];
#pragma unroll
    for (int i = 0; i < 8; i++)
#pragma unroll
        for (int j = 0; j < 8; j++) acc[i][j] = 0.f;

    for (int k0 = 0; k0 < K; k0 += BK) {
#pragma unroll
        for (int i = 0; i < 2; i++) {
            int idx = tid + i * 256;
            int row = idx >> 2;
            int kq  = (idx & 3) * 4;
            int gr  = m0 + row;
            float4 v = make_float4(0.f, 0.f, 0.f, 0.f);
            if (gr < M) v = *reinterpret_cast<const float4*>(&A[(size_t)gr * K + k0 + kq]);
            if (IN_BR) {
                float4 b = *reinterpret_cast<const float4*>(&in_bias[k0 + kq]);
                v.x = fmaxf(v.x + b.x, 0.f);
                v.y = fmaxf(v.y + b.y, 0.f);
                v.z = fmaxf(v.z + b.z, 0.f);
                v.w = fmaxf(v.w + b.w, 0.f);
            }
            As[kq + 0][row] = v.x;
            As[kq + 1][row] = v.y;
            As[kq + 2][row] = v.z;
            As[kq + 3][row] = v.w;
        }
#pragma unroll
        for (int i = 0; i < 2; i++) {
            int idx = tid + i * 256;
            int kr  = idx >> 5;
            int nq  = (idx & 31) * 4;
            *reinterpret_cast<float4*>(&Bs[kr][nq]) =
                *reinterpret_cast<const float4*>(&W[(size_t)(k0 + kr) * BN + nq]);
        }
        __syncthreads();

#pragma unroll
        for (int k = 0; k < BK; k++) {
            float4 a0 = *reinterpret_cast<const float4*>(&As[k][ty * 4]);
            float4 a1 = *reinterpret_cast<const float4*>(&As[k][64 + ty * 4]);
            float4 b0 = *reinterpret_cast<const float4*>(&Bs[k][tx * 4]);
            float4 b1 = *reinterpret_cast<const float4*>(&Bs[k][64 + tx * 4]);
            float a[8] = {a0.x, a0.y, a0.z, a0.w, a1.x, a1.y, a1.z, a1.w};
            float b[8] = {b0.x, b0.y, b0.z, b0.w, b1.x, b1.y, b1.z, b1.w};
#pragma unroll
            for (int i = 0; i < 8; i++)
#pragma unroll
                for (int j = 0; j < 8; j++)
                    acc[i][j] = fmaf(a[i], b[j], acc[i][j]);
        }
        __syncthreads();
    }

#pragma unroll
    for (int i = 0; i < 8; i++) {
        int r = m0 + (i < 4 ? ty * 4 + i : 64 + ty * 4 + (i - 4));
        if (r < M) {
            float4 v0 = make_float4(acc[i][0], acc[i][1], acc[i][2], acc[i][3]);
            float4 v1 = make_float4(acc[i][4], acc[i][5], acc[i][6], acc[i][7]);
            if (OUT_BR) {
                float4 c0 = *reinterpret_cast<const float4*>(&out_bias[tx * 4]);
                float4 c1 = *reinterpret_cast<const float4*>(&out_bias[64 + tx * 4]);
                v0.x = fmaxf(v0.x + c0.x, 0.f); v0.y = fmaxf(v0.y + c0.y, 0.f);
                v0.z = fmaxf(v0.z + c0.z, 0.f); v0.w = fmaxf(v0.w + c0.w, 0.f);
                v1.x = fmaxf(v1.x + c1.x, 0.f); v1.y = fmaxf(v1.y + c1.y, 0.f);
                v1.z = fmaxf(v1.z + c1.z, 0.f); v1.w = fmaxf(v1.w + c1.w, 0.f);
            }
            *reinterpret_cast<float4*>(&C[(size_t)r * BN + tx * 4]) = v0;
            *reinterpret_cast<float4*>(&C[(size_t)r * BN + 64 + tx * 4]) = v1;
        }
    }
}

// ---------------- logits + softmax: out[n] = softmax(a[n]@Wl2 + bl2) ----------------
// Half-wave per node: lane o in 0..31 owns output o. a-row held as float4
// fragments, broadcast across the half-wave via shfl; Wl2 staged in LDS.
__global__ __launch_bounds__(256) void logits_kernel(
    const float* __restrict__ a, const float* __restrict__ Wl2,
    const float* __restrict__ bl2, float* __restrict__ out, int M)
{
    __shared__ float sW2[128 * 32];
    const int tid = threadIdx.x;
    for (int i = tid * 4; i < 128 * 32; i += 256 * 4)
        *reinterpret_cast<float4*>(&sW2[i]) = *reinterpret_cast<const float4*>(&Wl2[i]);
    __syncthreads();

    const int lane = tid & 63;
    const int half = lane >> 5;          // 0/1 within the wave
    const int o = lane & 31;
    const int hw = tid >> 5;             // half-wave id in block: 0..7
    const float lb = bl2[o];
    const int nhw = gridDim.x * 8;

    for (int n = blockIdx.x * 8 + hw; n < M; n += nhw) {
        float4 af = *reinterpret_cast<const float4*>(&a[(size_t)n * 128 + o * 4]);
        float p = 0.f;
#pragma unroll
        for (int c = 0; c < 32; c++) {
            int srcl = (half << 5) + c;
            float v0 = __shfl(af.x, srcl);
            float v1 = __shfl(af.y, srcl);
            float v2 = __shfl(af.z, srcl);
            float v3 = __shfl(af.w, srcl);
            int k = c * 4;
            p = fmaf(v0, sW2[(k + 0) * 32 + o], p);
            p = fmaf(v1, sW2[(k + 1) * 32 + o], p);
            p = fmaf(v2, sW2[(k + 2) * 32 + o], p);
            p = fmaf(v3, sW2[(k + 3) * 32 + o], p);
        }
        float l = p + lb;
        float m = l;
#pragma unroll
        for (int s = 16; s >= 1; s >>= 1) m = fmaxf(m, __shfl_xor(m, s));
        float e = __expf(l - m);
        float ssum = e;
#pragma unroll
        for (int s = 16; s >= 1; s >>= 1) ssum += __shfl_xor(ssum, s);
        out[(size_t)n * 32 + o] = e / ssum;
    }
}

// ---------------------------------------------------------------------------
extern "C" void kernel_launch(void* const* d_in, const int* in_sizes, int n_in,
                              void* d_out, int out_size, void* d_ws, size_t ws_size,
                              hipStream_t stream) {
    const float* x   = (const float*)d_in[0];
    const int*   ei  = (const int*)d_in[1];
    const float* ew  = (const float*)d_in[2];
    const float* Wp  = (const float*)d_in[3];
    const float* bp  = (const float*)d_in[4];
    const float* W1  = (const float*)d_in[5];
    const float* b1  = (const float*)d_in[6];
    const float* W2  = (const float*)d_in[7];
    const float* b2  = (const float*)d_in[8];
    const float* Wl1 = (const float*)d_in[9];
    const float* bl1 = (const float*)d_in[10];
    const float* Wl2 = (const float*)d_in[11];
    const float* bl2 = (const float*)d_in[12];
    float* out = (float*)d_out;

    const int M = in_sizes[0] / 256;   // 100000 nodes
    const int E = in_sizes[2];         // 1600000 edges
    const int* srcp = ei;
    const int* dstp = ei + E;

    // ---- workspace layout ----
    char* ws = (char*)d_ws;
    size_t off = 0;
    auto alloc = [&](size_t bytes) { void* p = ws + off; off = (off + bytes + 255) & ~(size_t)255; return p; };
    float* dinv   = (float*)alloc((size_t)M * 4);
    int*   cnt    = (int*)  alloc((size_t)M * 4);
    int*   rowptr = (int*)  alloc((size_t)(M + 1) * 4);
    int*   cur    = (int*)  alloc((size_t)M * 4);
    int*   bsum   = (int*)  alloc((size_t)4096 * 4);
    int2*  pairs  = (int2*) alloc((size_t)E * 8);
    float* bufA   = (float*)alloc((size_t)M * 128 * 4);
    float* bufB   = (float*)alloc((size_t)M * 128 * 4);

    const int ntiles = (M + 2047) / 2048;

    // ---- CSR build (once; reused for both GCN layers) ----
    hipMemsetAsync(dinv, 0, (size_t)M * 4, stream);
    hipMemsetAsync(cnt, 0, (size_t)M * 4, stream);
    deg_cnt_kernel<<<(E + 255) / 256, 256, 0, stream>>>(dstp, ew, dinv, cnt, E);
    dinv_kernel<<<(M + 255) / 256, 256, 0, stream>>>(dinv, M);
    scan_reduce<<<ntiles, 256, 0, stream>>>(cnt, bsum, M);
    scan_bsum<<<1, 64, 0, stream>>>(bsum, rowptr + M, ntiles);
    scan_down<<<ntiles, 256, 0, stream>>>(cnt, bsum, rowptr, cur, M);
    reorder_kernel<<<(E + 255) / 256, 256, 0, stream>>>(srcp, dstp, ew, dinv, cur, pairs, E);

    const int gblocks = (M + 127) / 128;
    const int hblocks = (int)(((size_t)M * 32 + 255) / 256);

    // h0 = relu(x @ Wp + bp)
    gemm_f32<256, false, true><<<gblocks, 256, 0, stream>>>(x, Wp, nullptr, bp, bufA, M);

    // ---- GCN layer 1 ----
    gemm_f32<128, false, false><<<gblocks, 256, 0, stream>>>(bufA, W1, nullptr, nullptr, bufB, M);
    gather_kernel<<<hblocks, 256, 0, stream>>>(rowptr, pairs, dinv, bufB, bufA, M);

    // ---- GCN layer 2 (relu(agg1+b1) fused into GEMM input) ----
    gemm_f32<128, true, false><<<gblocks, 256, 0, stream>>>(bufA, W2, b1, nullptr, bufB, M);
    gather_kernel<<<hblocks, 256, 0, stream>>>(rowptr, pairs, dinv, bufB, bufA, M);

    // ---- head: a = relu(relu(agg2+b2)@Wl1 + bl1), then logits+softmax ----
    gemm_f32<128, true, true><<<gblocks, 256, 0, stream>>>(bufA, Wl1, b2, bl1, bufB, M);
    logits_kernel<<<1024, 256, 0, stream>>>(bufB, Wl2, bl2, out, M);
}

// Round 5
// 790.872 us; speedup vs baseline: 7.6008x; 1.2096x over previous
//
#include <hip/hip_runtime.h>

// ---------------------------------------------------------------------------
// GCN forward: proj GEMM -> (GEMM + CSR-gather agg) x2 -> head GEMM ->
// logits+softmax.
// Round 4: (a) deg+cnt fused into ONE u64 atomic per edge (fixed-point deg in
// low32 - exact integer accumulation; count in high32). (b) GEMMs moved to
// MFMA via split-bf16 (hi/lo, 3 products) with fp32 accumulation.
// ---------------------------------------------------------------------------

typedef __attribute__((ext_vector_type(8))) short bf16x8;
typedef __attribute__((ext_vector_type(4))) short bf16x4;
typedef __attribute__((ext_vector_type(4))) float f32x4;

__device__ __forceinline__ void atomAddF(float* p, float v) {
    unsafeAtomicAdd(p, v);
}

__device__ __forceinline__ ushort bf16_rne(float x) {
    unsigned int u = __float_as_uint(x);
    return (ushort)((u + 0x7FFFu + ((u >> 16) & 1u)) >> 16);
}

// LDS column swizzle: permute 8-wide k-blocks by row bits to spread banks.
// Applied identically on write (4-aligned runs) and read (8-aligned runs).
__device__ __forceinline__ int swz(int row, int k) {
    return k ^ (((row >> 1) & 3) << 3);
}

// ---------------- deg+cnt in one u64 atomic ----------------
// low 32: sum of ew in 2^24 fixed point (exact); high 32: edge count.
__global__ void deg_cnt_kernel(const int* __restrict__ dst, const float* __restrict__ ew,
                               unsigned long long* __restrict__ packed, int E) {
    int e = blockIdx.x * blockDim.x + threadIdx.x;
    if (e < E) {
        int d = dst[e];
        unsigned int fx = __float2uint_rn(ew[e] * 16777216.0f);
        atomicAdd(&packed[d], (1ULL << 32) | (unsigned long long)fx);
    }
}

__global__ void dinv_kernel(const unsigned long long* __restrict__ packed,
                            float* __restrict__ dinv, int N) {
    int i = blockIdx.x * blockDim.x + threadIdx.x;
    if (i < N) {
        float deg = (float)(unsigned int)(packed[i] & 0xFFFFFFFFull) * (1.0f / 16777216.0f);
        dinv[i] = 1.0f / sqrtf(deg + 1.0f);   // self-loop adds 1
    }
}

// ---------------- hierarchical exclusive scan over cnt (= packed>>32) ----------------
__global__ __launch_bounds__(256) void scan_reduce(const unsigned long long* __restrict__ packed,
                                                   int* __restrict__ bsum, int M) {
    __shared__ int wsum[4];
    const int t = threadIdx.x;
    const int base = blockIdx.x * 2048 + t * 8;
    int s = 0;
#pragma unroll
    for (int j = 0; j < 8; j++) {
        int i = base + j;
        if (i < M) s += (int)(packed[i] >> 32);
    }
#pragma unroll
    for (int off = 1; off < 64; off <<= 1) s += __shfl_xor(s, off);
    if ((t & 63) == 0) wsum[t >> 6] = s;
    __syncthreads();
    if (t == 0) bsum[blockIdx.x] = wsum[0] + wsum[1] + wsum[2] + wsum[3];
}

__global__ void scan_bsum(int* __restrict__ bsum, int* __restrict__ rowptr_last, int nb) {
    const int lane = threadIdx.x;   // 64 lanes
    const int chunk = (nb + 63) / 64;
    const int b0 = lane * chunk;
    const int b1 = min(b0 + chunk, nb);
    int s = 0;
    for (int i = b0; i < b1; i++) s += bsum[i];
    int inc = s;
#pragma unroll
    for (int off = 1; off < 64; off <<= 1) {
        int u = __shfl_up(inc, off);
        if (lane >= off) inc += u;
    }
    int run = inc - s;
    for (int i = b0; i < b1; i++) {
        int v = bsum[i];
        bsum[i] = run;
        run += v;
    }
    if (lane == 63) *rowptr_last = inc;   // total = E
}

__global__ __launch_bounds__(256) void scan_down(const unsigned long long* __restrict__ packed,
                                                 const int* __restrict__ bsum,
                                                 int* __restrict__ rowptr,
                                                 int* __restrict__ cur, int M) {
    __shared__ int wpre[4];
    const int t = threadIdx.x;
    const int lane = t & 63;
    const int w = t >> 6;
    const int base = blockIdx.x * 2048 + t * 8;
    int c[8];
    int s = 0;
#pragma unroll
    for (int j = 0; j < 8; j++) {
        int i = base + j;
        c[j] = (i < M) ? (int)(packed[i] >> 32) : 0;
        s += c[j];
    }
    int inc = s;
#pragma unroll
    for (int off = 1; off < 64; off <<= 1) {
        int u = __shfl_up(inc, off);
        if (lane >= off) inc += u;
    }
    if (lane == 63) wpre[w] = inc;
    __syncthreads();
    int woff = 0;
#pragma unroll
    for (int i = 0; i < 4; i++)
        if (i < w) woff += wpre[i];
    int run = bsum[blockIdx.x] + woff + (inc - s);
#pragma unroll
    for (int j = 0; j < 8; j++) {
        int i = base + j;
        if (i < M) {
            rowptr[i] = run;
            cur[i] = run;
            run += c[j];
        }
    }
}

// ---------------- reorder edges into CSR buckets: pairs[pos] = (src, norm) ----------------
__global__ void reorder_kernel(const int* __restrict__ src, const int* __restrict__ dst,
                               const float* __restrict__ ew, const float* __restrict__ dinv,
                               int* __restrict__ cur, int2* __restrict__ pairs, int E) {
    int e = blockIdx.x * blockDim.x + threadIdx.x;
    if (e < E) {
        int s = src[e], d = dst[e];
        float w = dinv[s] * ew[e] * dinv[d];
        int pos = atomicAdd(&cur[d], 1);
        pairs[pos] = make_int2(s, __float_as_int(w));
    }
}

// ---------------- CSR gather: agg[n] = dinv[n]^2*hW[n] + sum_e w_e * hW[src_e] ----------------
__global__ __launch_bounds__(256) void gather_kernel(
    const int* __restrict__ rowptr, const int2* __restrict__ pairs,
    const float* __restrict__ dinv, const float* __restrict__ hW,
    float* __restrict__ agg, int M)
{
    int gid = blockIdx.x * blockDim.x + threadIdx.x;
    int n = gid >> 5;
    int c = (gid & 31) * 4;
    if (n >= M) return;
    int beg = rowptr[n], end = rowptr[n + 1];
    float di = dinv[n];
    float s = di * di;
    float4 v = *reinterpret_cast<const float4*>(&hW[(size_t)n * 128 + c]);
    float4 acc0 = make_float4(s * v.x, s * v.y, s * v.z, s * v.w);
    float4 acc1 = make_float4(0.f, 0.f, 0.f, 0.f);

    int e = beg;
    for (; e + 4 <= end; e += 4) {
        int2 p0 = pairs[e + 0];
        int2 p1 = pairs[e + 1];
        int2 p2 = pairs[e + 2];
        int2 p3 = pairs[e + 3];
        float4 h0 = *reinterpret_cast<const float4*>(&hW[(size_t)p0.x * 128 + c]);
        float4 h1 = *reinterpret_cast<const float4*>(&hW[(size_t)p1.x * 128 + c]);
        float4 h2 = *reinterpret_cast<const float4*>(&hW[(size_t)p2.x * 128 + c]);
        float4 h3 = *reinterpret_cast<const float4*>(&hW[(size_t)p3.x * 128 + c]);
        float w0 = __int_as_float(p0.y), w1 = __int_as_float(p1.y);
        float w2 = __int_as_float(p2.y), w3 = __int_as_float(p3.y);
        acc0.x = fmaf(w0, h0.x, acc0.x); acc0.y = fmaf(w0, h0.y, acc0.y);
        acc0.z = fmaf(w0, h0.z, acc0.z); acc0.w = fmaf(w0, h0.w, acc0.w);
        acc1.x = fmaf(w1, h1.x, acc1.x); acc1.y = fmaf(w1, h1.y, acc1.y);
        acc1.z = fmaf(w1, h1.z, acc1.z); acc1.w = fmaf(w1, h1.w, acc1.w);
        acc0.x = fmaf(w2, h2.x, acc0.x); acc0.y = fmaf(w2, h2.y, acc0.y);
        acc0.z = fmaf(w2, h2.z, acc0.z); acc0.w = fmaf(w2, h2.w, acc0.w);
        acc1.x = fmaf(w3, h3.x, acc1.x); acc1.y = fmaf(w3, h3.y, acc1.y);
        acc1.z = fmaf(w3, h3.z, acc1.z); acc1.w = fmaf(w3, h3.w, acc1.w);
    }
    for (; e < end; e++) {
        int2 p = pairs[e];
        float w = __int_as_float(p.y);
        float4 h = *reinterpret_cast<const float4*>(&hW[(size_t)p.x * 128 + c]);
        acc0.x = fmaf(w, h.x, acc0.x);
        acc0.y = fmaf(w, h.y, acc0.y);
        acc0.z = fmaf(w, h.z, acc0.z);
        acc0.w = fmaf(w, h.w, acc0.w);
    }
    acc0.x += acc1.x; acc0.y += acc1.y; acc0.z += acc1.z; acc0.w += acc1.w;
    *reinterpret_cast<float4*>(&agg[(size_t)n * 128 + c]) = acc0;
}

// ---------------- split-bf16 MFMA GEMM: C[M,128] = op(A[M,K]) @ W[K,128] ----------------
// BM=128, BN=128, BK=32; 4 waves, each owns a 64x64 quadrant as 4x4 16x16 tiles.
// A,W decomposed to bf16 hi+lo; 3 MFMA products (hh, hl, lh) per tile-pair.
template<int K, bool IN_BR, bool OUT_BR>
__global__ __launch_bounds__(256) void gemm_mfma(
    const float* __restrict__ A, const float* __restrict__ W,
    const float* __restrict__ in_bias, const float* __restrict__ out_bias,
    float* __restrict__ C, int M)
{
    __shared__ ushort Ah[128][40], Al[128][40], Bh[128][40], Bl[128][40];

    const int tid = threadIdx.x;
    const int lane = tid & 63;
    const int wave = tid >> 6;
    const int wm = (wave >> 1) * 64;    // wave quadrant row base (local)
    const int wn = (wave & 1) * 64;     // wave quadrant col base (local)
    const int m0 = blockIdx.x * 128;

    f32x4 acc[4][4] = {};

    // staging thread layout
    const int ar = tid >> 1;            // A row 0..127
    const int ak = (tid & 1) * 16;      // A k base {0,16}
    const int bn = (tid & 31) * 4;      // B n base (4 cols)
    const int bk = (tid >> 5) * 4;      // B k base (4 rows)

    const int fm = lane & 15;           // frag m/n index
    const int fk = (lane >> 4) * 8;     // frag k-block base

    for (int k0 = 0; k0 < K; k0 += 32) {
        __syncthreads();
        // ---- stage A tile (128 x 32) ----
        {
            const bool valid = (m0 + ar) < M;
            const float* srcp = &A[(size_t)(m0 + ar) * K + k0 + ak];
#pragma unroll
            for (int q = 0; q < 2; q++) {
                float vv[8];
                if (valid) {
                    *reinterpret_cast<float4*>(&vv[0]) = *reinterpret_cast<const float4*>(srcp + q * 8);
                    *reinterpret_cast<float4*>(&vv[4]) = *reinterpret_cast<const float4*>(srcp + q * 8 + 4);
                } else {
#pragma unroll
                    for (int j = 0; j < 8; j++) vv[j] = 0.f;
                }
                if (IN_BR) {
                    const float* bp_ = &in_bias[k0 + ak + q * 8];
#pragma unroll
                    for (int j = 0; j < 8; j++) vv[j] = fmaxf(vv[j] + bp_[j], 0.f);
                }
#pragma unroll
                for (int h = 0; h < 2; h++) {   // two 4-runs
                    ushort hh[4], ll[4];
#pragma unroll
                    for (int j = 0; j < 4; j++) {
                        float x = vv[h * 4 + j];
                        ushort hi = bf16_rne(x);
                        float fhi = __uint_as_float((unsigned int)hi << 16);
                        hh[j] = hi;
                        ll[j] = bf16_rne(x - fhi);
                    }
                    int col = swz(ar, ak + q * 8 + h * 4);
                    *reinterpret_cast<bf16x4*>(&Ah[ar][col]) = *reinterpret_cast<bf16x4*>(hh);
                    *reinterpret_cast<bf16x4*>(&Al[ar][col]) = *reinterpret_cast<bf16x4*>(ll);
                }
            }
        }
        // ---- stage B tile (32 x 128), transposed into [n][k] ----
        {
            float rr[4][4];
#pragma unroll
            for (int i = 0; i < 4; i++)
                *reinterpret_cast<float4*>(rr[i]) =
                    *reinterpret_cast<const float4*>(&W[(size_t)(k0 + bk + i) * 128 + bn]);
#pragma unroll
            for (int j = 0; j < 4; j++) {
                ushort hh[4], ll[4];
#pragma unroll
                for (int i = 0; i < 4; i++) {
                    float x = rr[i][j];
                    ushort hi = bf16_rne(x);
                    float fhi = __uint_as_float((unsigned int)hi << 16);
                    hh[i] = hi;
                    ll[i] = bf16_rne(x - fhi);
                }
                int n = bn + j;
                int col = swz(n, bk);
                *reinterpret_cast<bf16x4*>(&Bh[n][col]) = *reinterpret_cast<bf16x4*>(hh);
                *reinterpret_cast<bf16x4*>(&Bl[n][col]) = *reinterpret_cast<bf16x4*>(ll);
            }
        }
        __syncthreads();

        // ---- fragments + MFMA ----
        bf16x8 ah[4], al[4], bh[4], bl[4];
#pragma unroll
        for (int t = 0; t < 4; t++) {
            int am = wm + t * 16 + fm;
            int ac = swz(am, fk);
            ah[t] = *reinterpret_cast<const bf16x8*>(&Ah[am][ac]);
            al[t] = *reinterpret_cast<const bf16x8*>(&Al[am][ac]);
            int nn = wn + t * 16 + fm;
            int bc = swz(nn, fk);
            bh[t] = *reinterpret_cast<const bf16x8*>(&Bh[nn][bc]);
            bl[t] = *reinterpret_cast<const bf16x8*>(&Bl[nn][bc]);
        }
#pragma unroll
        for (int i = 0; i < 4; i++)
#pragma unroll
            for (int j = 0; j < 4; j++) {
                acc[i][j] = __builtin_amdgcn_mfma_f32_16x16x32_bf16(ah[i], bh[j], acc[i][j], 0, 0, 0);
                acc[i][j] = __builtin_amdgcn_mfma_f32_16x16x32_bf16(ah[i], bl[j], acc[i][j], 0, 0, 0);
                acc[i][j] = __builtin_amdgcn_mfma_f32_16x16x32_bf16(al[i], bh[j], acc[i][j], 0, 0, 0);
            }
    }

    // ---- epilogue: D[row=(lane>>4)*4+q][col=lane&15] per 16x16 tile ----
#pragma unroll
    for (int i = 0; i < 4; i++) {
        int rbase = m0 + wm + i * 16 + (lane >> 4) * 4;
#pragma unroll
        for (int q = 0; q < 4; q++) {
            int r = rbase + q;
            if (r < M) {
#pragma unroll
                for (int j = 0; j < 4; j++) {
                    int cidx = wn + j * 16 + (lane & 15);
                    float v = acc[i][j][q];
                    if (OUT_BR) v = fmaxf(v + out_bias[cidx], 0.f);
                    C[(size_t)r * 128 + cidx] = v;
                }
            }
        }
    }
}

// ---------------- logits + softmax: out[n] = softmax(a[n]@Wl2 + bl2) ----------------
__global__ __launch_bounds__(256) void logits_kernel(
    const float* __restrict__ a, const float* __restrict__ Wl2,
    const float* __restrict__ bl2, float* __restrict__ out, int M)
{
    __shared__ float sW2[128 * 32];
    const int tid = threadIdx.x;
    for (int i = tid * 4; i < 128 * 32; i += 256 * 4)
        *reinterpret_cast<float4*>(&sW2[i]) = *reinterpret_cast<const float4*>(&Wl2[i]);
    __syncthreads();

    const int lane = tid & 63;
    const int half = lane >> 5;
    const int o = lane & 31;
    const int hw = tid >> 5;
    const float lb = bl2[o];
    const int nhw = gridDim.x * 8;

    for (int n = blockIdx.x * 8 + hw; n < M; n += nhw) {
        float4 af = *reinterpret_cast<const float4*>(&a[(size_t)n * 128 + o * 4]);
        float p = 0.f;
#pragma unroll
        for (int c = 0; c < 32; c++) {
            int srcl = (half << 5) + c;
            float v0 = __shfl(af.x, srcl);
            float v1 = __shfl(af.y, srcl);
            float v2 = __shfl(af.z, srcl);
            float v3 = __shfl(af.w, srcl);
            int k = c * 4;
            p = fmaf(v0, sW2[(k + 0) * 32 + o], p);
            p = fmaf(v1, sW2[(k + 1) * 32 + o], p);
            p = fmaf(v2, sW2[(k + 2) * 32 + o], p);
            p = fmaf(v3, sW2[(k + 3) * 32 + o], p);
        }
        float l = p + lb;
        float m = l;
#pragma unroll
        for (int s = 16; s >= 1; s >>= 1) m = fmaxf(m, __shfl_xor(m, s));
        float e = __expf(l - m);
        float ssum = e;
#pragma unroll
        for (int s = 16; s >= 1; s >>= 1) ssum += __shfl_xor(ssum, s);
        out[(size_t)n * 32 + o] = e / ssum;
    }
}

// ---------------------------------------------------------------------------
extern "C" void kernel_launch(void* const* d_in, const int* in_sizes, int n_in,
                              void* d_out, int out_size, void* d_ws, size_t ws_size,
                              hipStream_t stream) {
    const float* x   = (const float*)d_in[0];
    const int*   ei  = (const int*)d_in[1];
    const float* ew  = (const float*)d_in[2];
    const float* Wp  = (const float*)d_in[3];
    const float* bp  = (const float*)d_in[4];
    const float* W1  = (const float*)d_in[5];
    const float* b1  = (const float*)d_in[6];
    const float* W2  = (const float*)d_in[7];
    const float* b2  = (const float*)d_in[8];
    const float* Wl1 = (const float*)d_in[9];
    const float* bl1 = (const float*)d_in[10];
    const float* Wl2 = (const float*)d_in[11];
    const float* bl2 = (const float*)d_in[12];
    float* out = (float*)d_out;

    const int M = in_sizes[0] / 256;   // 100000 nodes
    const int E = in_sizes[2];         // 1600000 edges
    const int* srcp = ei;
    const int* dstp = ei + E;

    // ---- workspace layout ----
    char* ws = (char*)d_ws;
    size_t off = 0;
    auto alloc = [&](size_t bytes) { void* p = ws + off; off = (off + bytes + 255) & ~(size_t)255; return p; };
    unsigned long long* packed = (unsigned long long*)alloc((size_t)M * 8);
    float* dinv   = (float*)alloc((size_t)M * 4);
    int*   rowptr = (int*)  alloc((size_t)(M + 1) * 4);
    int*   cur    = (int*)  alloc((size_t)M * 4);
    int*   bsum   = (int*)  alloc((size_t)4096 * 4);
    int2*  pairs  = (int2*) alloc((size_t)E * 8);
    float* bufA   = (float*)alloc((size_t)M * 128 * 4);
    float* bufB   = (float*)alloc((size_t)M * 128 * 4);

    const int ntiles = (M + 2047) / 2048;

    // ---- CSR build (once; reused for both GCN layers) ----
    hipMemsetAsync(packed, 0, (size_t)M * 8, stream);
    deg_cnt_kernel<<<(E + 255) / 256, 256, 0, stream>>>(dstp, ew, packed, E);
    dinv_kernel<<<(M + 255) / 256, 256, 0, stream>>>(packed, dinv, M);
    scan_reduce<<<ntiles, 256, 0, stream>>>(packed, bsum, M);
    scan_bsum<<<1, 64, 0, stream>>>(bsum, rowptr + M, ntiles);
    scan_down<<<ntiles, 256, 0, stream>>>(packed, bsum, rowptr, cur, M);
    reorder_kernel<<<(E + 255) / 256, 256, 0, stream>>>(srcp, dstp, ew, dinv, cur, pairs, E);

    const int gblocks = (M + 127) / 128;
    const int hblocks = (int)(((size_t)M * 32 + 255) / 256);

    // h0 = relu(x @ Wp + bp)
    gemm_mfma<256, false, true><<<gblocks, 256, 0, stream>>>(x, Wp, nullptr, bp, bufA, M);

    // ---- GCN layer 1 ----
    gemm_mfma<128, false, false><<<gblocks, 256, 0, stream>>>(bufA, W1, nullptr, nullptr, bufB, M);
    gather_kernel<<<hblocks, 256, 0, stream>>>(rowptr, pairs, dinv, bufB, bufA, M);

    // ---- GCN layer 2 (relu(agg1+b1) fused into GEMM input) ----
    gemm_mfma<128, true, false><<<gblocks, 256, 0, stream>>>(bufA, W2, b1, nullptr, bufB, M);
    gather_kernel<<<hblocks, 256, 0, stream>>>(rowptr, pairs, dinv, bufB, bufA, M);

    // ---- head: a = relu(relu(agg2+b2)@Wl1 + bl1), then logits+softmax ----
    gemm_mfma<128, true, true><<<gblocks, 256, 0, stream>>>(bufA, Wl1, b2, bl1, bufB, M);
    logits_kernel<<<1024, 256, 0, stream>>>(bufB, Wl2, bl2, out, M);
}

// Round 6
// 749.350 us; speedup vs baseline: 8.0220x; 1.0554x over previous
//
#include <hip/hip_runtime.h>

// ---------------------------------------------------------------------------
// GCN forward. Round 5:
//  - weights pre-split once into transposed bf16 hi/lo planes (was: every
//    block re-split W in LDS staging)
//  - activations produced as bf16 hi/lo planes by proj/gather epilogues
//    (bias+relu fused there), so K=128 GEMM staging is pure copies
//  - reorder uses ranks captured from deg_cnt's atomic return (no 2nd atomic)
// ---------------------------------------------------------------------------

typedef __attribute__((ext_vector_type(8))) short bf16x8;
typedef __attribute__((ext_vector_type(4))) short bf16x4;
typedef __attribute__((ext_vector_type(4))) float f32x4;

__device__ __forceinline__ ushort bf16_rne(float x) {
    unsigned int u = __float_as_uint(x);
    return (ushort)((u + 0x7FFFu + ((u >> 16) & 1u)) >> 16);
}

// LDS column swizzle: permute 8-wide k-blocks by row bits (XOR bits 3..4).
__device__ __forceinline__ int swz(int row, int k) {
    return k ^ (((row >> 1) & 3) << 3);
}

// ---------------- deg+cnt in one u64 atomic; rank = prior count ----------------
__global__ void deg_cnt_kernel(const int* __restrict__ dst, const float* __restrict__ ew,
                               unsigned long long* __restrict__ packed,
                               int* __restrict__ rank, int E) {
    int e = blockIdx.x * blockDim.x + threadIdx.x;
    if (e < E) {
        int d = dst[e];
        unsigned int fx = __float2uint_rn(ew[e] * 16777216.0f);
        unsigned long long old = atomicAdd(&packed[d], (1ULL << 32) | (unsigned long long)fx);
        rank[e] = (int)(old >> 32);
    }
}

__global__ void dinv_kernel(const unsigned long long* __restrict__ packed,
                            float* __restrict__ dinv, int N) {
    int i = blockIdx.x * blockDim.x + threadIdx.x;
    if (i < N) {
        float deg = (float)(unsigned int)(packed[i] & 0xFFFFFFFFull) * (1.0f / 16777216.0f);
        dinv[i] = 1.0f / sqrtf(deg + 1.0f);
    }
}

// ---------------- hierarchical exclusive scan over cnt (= packed>>32) ----------------
__global__ __launch_bounds__(256) void scan_reduce(const unsigned long long* __restrict__ packed,
                                                   int* __restrict__ bsum, int M) {
    __shared__ int wsum[4];
    const int t = threadIdx.x;
    const int base = blockIdx.x * 2048 + t * 8;
    int s = 0;
#pragma unroll
    for (int j = 0; j < 8; j++) {
        int i = base + j;
        if (i < M) s += (int)(packed[i] >> 32);
    }
#pragma unroll
    for (int off = 1; off < 64; off <<= 1) s += __shfl_xor(s, off);
    if ((t & 63) == 0) wsum[t >> 6] = s;
    __syncthreads();
    if (t == 0) bsum[blockIdx.x] = wsum[0] + wsum[1] + wsum[2] + wsum[3];
}

__global__ void scan_bsum(int* __restrict__ bsum, int* __restrict__ rowptr_last, int nb) {
    const int lane = threadIdx.x;
    const int chunk = (nb + 63) / 64;
    const int b0 = lane * chunk;
    const int b1 = min(b0 + chunk, nb);
    int s = 0;
    for (int i = b0; i < b1; i++) s += bsum[i];
    int inc = s;
#pragma unroll
    for (int off = 1; off < 64; off <<= 1) {
        int u = __shfl_up(inc, off);
        if (lane >= off) inc += u;
    }
    int run = inc - s;
    for (int i = b0; i < b1; i++) {
        int v = bsum[i];
        bsum[i] = run;
        run += v;
    }
    if (lane == 63) *rowptr_last = inc;
}

__global__ __launch_bounds__(256) void scan_down(const unsigned long long* __restrict__ packed,
                                                 const int* __restrict__ bsum,
                                                 int* __restrict__ rowptr, int M) {
    __shared__ int wpre[4];
    const int t = threadIdx.x;
    const int lane = t & 63;
    const int w = t >> 6;
    const int base = blockIdx.x * 2048 + t * 8;
    int c[8];
    int s = 0;
#pragma unroll
    for (int j = 0; j < 8; j++) {
        int i = base + j;
        c[j] = (i < M) ? (int)(packed[i] >> 32) : 0;
        s += c[j];
    }
    int inc = s;
#pragma unroll
    for (int off = 1; off < 64; off <<= 1) {
        int u = __shfl_up(inc, off);
        if (lane >= off) inc += u;
    }
    if (lane == 63) wpre[w] = inc;
    __syncthreads();
    int woff = 0;
#pragma unroll
    for (int i = 0; i < 4; i++)
        if (i < w) woff += wpre[i];
    int run = bsum[blockIdx.x] + woff + (inc - s);
#pragma unroll
    for (int j = 0; j < 8; j++) {
        int i = base + j;
        if (i < M) {
            rowptr[i] = run;
            run += c[j];
        }
    }
}

// ---------------- reorder (atomic-free): pairs[rowptr[d]+rank[e]] ----------------
__global__ void reorder_kernel(const int* __restrict__ src, const int* __restrict__ dst,
                               const float* __restrict__ ew, const float* __restrict__ dinv,
                               const int* __restrict__ rowptr, const int* __restrict__ rank,
                               int2* __restrict__ pairs, int E) {
    int e = blockIdx.x * blockDim.x + threadIdx.x;
    if (e < E) {
        int s = src[e], d = dst[e];
        float w = dinv[s] * ew[e] * dinv[d];
        pairs[rowptr[d] + rank[e]] = make_int2(s, __float_as_int(w));
    }
}

// ---------------- weight pre-split: W[K][128] -> planes [n][K] hi/lo ----------------
__global__ void split_w_kernel(const float* __restrict__ W, ushort* __restrict__ ph,
                               ushort* __restrict__ pl, int total, int Kdim) {
    int id = blockIdx.x * blockDim.x + threadIdx.x;
    if (id < total) {
        int k = id >> 7;          // N == 128 always
        int n = id & 127;
        float x = W[id];
        ushort hi = bf16_rne(x);
        float fhi = __uint_as_float((unsigned int)hi << 16);
        ph[n * Kdim + k] = hi;
        pl[n * Kdim + k] = bf16_rne(x - fhi);
    }
}

// ---------------- CSR gather + bias/relu + hi/lo plane epilogue ----------------
// agg[n] = dinv[n]^2*hW[n] + sum_e w_e*hW[src_e]; t = relu(agg + bias);
// write bf16 hi/lo planes (feeds the next MFMA GEMM).
__global__ __launch_bounds__(256) void gather_kernel(
    const int* __restrict__ rowptr, const int2* __restrict__ pairs,
    const float* __restrict__ dinv, const float* __restrict__ hW,
    const float* __restrict__ bias, ushort* __restrict__ ph,
    ushort* __restrict__ pl, int M)
{
    int gid = blockIdx.x * blockDim.x + threadIdx.x;
    int n = gid >> 5;
    int c = (gid & 31) * 4;
    if (n >= M) return;
    int beg = rowptr[n], end = rowptr[n + 1];
    float di = dinv[n];
    float s = di * di;
    float4 v = *reinterpret_cast<const float4*>(&hW[(size_t)n * 128 + c]);
    float4 acc0 = make_float4(s * v.x, s * v.y, s * v.z, s * v.w);
    float4 acc1 = make_float4(0.f, 0.f, 0.f, 0.f);

    int e = beg;
    for (; e + 4 <= end; e += 4) {
        int2 p0 = pairs[e + 0];
        int2 p1 = pairs[e + 1];
        int2 p2 = pairs[e + 2];
        int2 p3 = pairs[e + 3];
        float4 h0 = *reinterpret_cast<const float4*>(&hW[(size_t)p0.x * 128 + c]);
        float4 h1 = *reinterpret_cast<const float4*>(&hW[(size_t)p1.x * 128 + c]);
        float4 h2 = *reinterpret_cast<const float4*>(&hW[(size_t)p2.x * 128 + c]);
        float4 h3 = *reinterpret_cast<const float4*>(&hW[(size_t)p3.x * 128 + c]);
        float w0 = __int_as_float(p0.y), w1 = __int_as_float(p1.y);
        float w2 = __int_as_float(p2.y), w3 = __int_as_float(p3.y);
        acc0.x = fmaf(w0, h0.x, acc0.x); acc0.y = fmaf(w0, h0.y, acc0.y);
        acc0.z = fmaf(w0, h0.z, acc0.z); acc0.w = fmaf(w0, h0.w, acc0.w);
        acc1.x = fmaf(w1, h1.x, acc1.x); acc1.y = fmaf(w1, h1.y, acc1.y);
        acc1.z = fmaf(w1, h1.z, acc1.z); acc1.w = fmaf(w1, h1.w, acc1.w);
        acc0.x = fmaf(w2, h2.x, acc0.x); acc0.y = fmaf(w2, h2.y, acc0.y);
        acc0.z = fmaf(w2, h2.z, acc0.z); acc0.w = fmaf(w2, h2.w, acc0.w);
        acc1.x = fmaf(w3, h3.x, acc1.x); acc1.y = fmaf(w3, h3.y, acc1.y);
        acc1.z = fmaf(w3, h3.z, acc1.z); acc1.w = fmaf(w3, h3.w, acc1.w);
    }
    for (; e < end; e++) {
        int2 p = pairs[e];
        float w = __int_as_float(p.y);
        float4 h = *reinterpret_cast<const float4*>(&hW[(size_t)p.x * 128 + c]);
        acc0.x = fmaf(w, h.x, acc0.x);
        acc0.y = fmaf(w, h.y, acc0.y);
        acc0.z = fmaf(w, h.z, acc0.z);
        acc0.w = fmaf(w, h.w, acc0.w);
    }
    float4 b = *reinterpret_cast<const float4*>(&bias[c]);
    float t0 = fmaxf(acc0.x + acc1.x + b.x, 0.f);
    float t1 = fmaxf(acc0.y + acc1.y + b.y, 0.f);
    float t2 = fmaxf(acc0.z + acc1.z + b.z, 0.f);
    float t3 = fmaxf(acc0.w + acc1.w + b.w, 0.f);
    ushort h4[4], l4[4];
    float tt[4] = {t0, t1, t2, t3};
#pragma unroll
    for (int j = 0; j < 4; j++) {
        ushort hi = bf16_rne(tt[j]);
        float fhi = __uint_as_float((unsigned int)hi << 16);
        h4[j] = hi;
        l4[j] = bf16_rne(tt[j] - fhi);
    }
    *reinterpret_cast<bf16x4*>(&ph[(size_t)n * 128 + c]) = *reinterpret_cast<bf16x4*>(h4);
    *reinterpret_cast<bf16x4*>(&pl[(size_t)n * 128 + c]) = *reinterpret_cast<bf16x4*>(l4);
}

// ---------------- split-bf16 MFMA GEMM ----------------
// A_PRE: A supplied as hi/lo ushort planes (row stride K); else fp32 A split inline.
// OUT_PLANES: epilogue writes hi/lo planes (with OUT_BR bias+relu); else fp32.
template<int K, bool A_PRE, bool OUT_BR, bool OUT_PLANES>
__global__ __launch_bounds__(256) void gemm_mfma(
    const float* __restrict__ A,
    const ushort* __restrict__ Ahp, const ushort* __restrict__ Alp,
    const ushort* __restrict__ Bhp, const ushort* __restrict__ Blp,
    const float* __restrict__ out_bias,
    float* __restrict__ C, ushort* __restrict__ Chp, ushort* __restrict__ Clp,
    int M)
{
    __shared__ ushort Ah[128][40], Al[128][40], Bh[128][40], Bl[128][40];

    const int tid = threadIdx.x;
    const int lane = tid & 63;
    const int wave = tid >> 6;
    const int wm = (wave >> 1) * 64;
    const int wn = (wave & 1) * 64;
    const int m0 = blockIdx.x * 128;

    f32x4 acc[4][4] = {};

    // staging thread layout (both A and B): row/n = tid>>1, k-half = (tid&1)*16
    const int sr = tid >> 1;
    const int sk = (tid & 1) * 16;

    const int fm = lane & 15;
    const int fk = (lane >> 4) * 8;

    for (int k0 = 0; k0 < K; k0 += 32) {
        __syncthreads();
        // ---- stage A tile (128 x 32) ----
        if (A_PRE) {
            const bool valid = (m0 + sr) < M;
            bf16x8 zero = {};
            bf16x8 h0 = zero, h1 = zero, l0 = zero, l1 = zero;
            if (valid) {
                const ushort* ph = &Ahp[(size_t)(m0 + sr) * K + k0 + sk];
                const ushort* pl = &Alp[(size_t)(m0 + sr) * K + k0 + sk];
                h0 = *reinterpret_cast<const bf16x8*>(ph);
                h1 = *reinterpret_cast<const bf16x8*>(ph + 8);
                l0 = *reinterpret_cast<const bf16x8*>(pl);
                l1 = *reinterpret_cast<const bf16x8*>(pl + 8);
            }
            *reinterpret_cast<bf16x8*>(&Ah[sr][swz(sr, sk)]) = h0;
            *reinterpret_cast<bf16x8*>(&Ah[sr][swz(sr, sk + 8)]) = h1;
            *reinterpret_cast<bf16x8*>(&Al[sr][swz(sr, sk)]) = l0;
            *reinterpret_cast<bf16x8*>(&Al[sr][swz(sr, sk + 8)]) = l1;
        } else {
            const bool valid = (m0 + sr) < M;
            const float* srcp = &A[(size_t)(m0 + sr) * K + k0 + sk];
#pragma unroll
            for (int q = 0; q < 2; q++) {
                float vv[8];
                if (valid) {
                    *reinterpret_cast<float4*>(&vv[0]) = *reinterpret_cast<const float4*>(srcp + q * 8);
                    *reinterpret_cast<float4*>(&vv[4]) = *reinterpret_cast<const float4*>(srcp + q * 8 + 4);
                } else {
#pragma unroll
                    for (int j = 0; j < 8; j++) vv[j] = 0.f;
                }
                ushort hh[8], ll[8];
#pragma unroll
                for (int j = 0; j < 8; j++) {
                    ushort hi = bf16_rne(vv[j]);
                    float fhi = __uint_as_float((unsigned int)hi << 16);
                    hh[j] = hi;
                    ll[j] = bf16_rne(vv[j] - fhi);
                }
                int col = swz(sr, sk + q * 8);
                *reinterpret_cast<bf16x8*>(&Ah[sr][col]) = *reinterpret_cast<bf16x8*>(hh);
                *reinterpret_cast<bf16x8*>(&Al[sr][col]) = *reinterpret_cast<bf16x8*>(ll);
            }
        }
        // ---- stage B tile (n 0..127, k0..k0+32) from transposed planes ----
        {
            const ushort* ph = &Bhp[(size_t)sr * K + k0 + sk];
            const ushort* pl = &Blp[(size_t)sr * K + k0 + sk];
            *reinterpret_cast<bf16x8*>(&Bh[sr][swz(sr, sk)]) = *reinterpret_cast<const bf16x8*>(ph);
            *reinterpret_cast<bf16x8*>(&Bh[sr][swz(sr, sk + 8)]) = *reinterpret_cast<const bf16x8*>(ph + 8);
            *reinterpret_cast<bf16x8*>(&Bl[sr][swz(sr, sk)]) = *reinterpret_cast<const bf16x8*>(pl);
            *reinterpret_cast<bf16x8*>(&Bl[sr][swz(sr, sk + 8)]) = *reinterpret_cast<const bf16x8*>(pl + 8);
        }
        __syncthreads();

        // ---- fragments + MFMA (hh + hl + lh) ----
        bf16x8 ah[4], al[4], bh[4], bl[4];
#pragma unroll
        for (int t = 0; t < 4; t++) {
            int am = wm + t * 16 + fm;
            int ac = swz(am, fk);
            ah[t] = *reinterpret_cast<const bf16x8*>(&Ah[am][ac]);
            al[t] = *reinterpret_cast<const bf16x8*>(&Al[am][ac]);
            int nn = wn + t * 16 + fm;
            int bc = swz(nn, fk);
            bh[t] = *reinterpret_cast<const bf16x8*>(&Bh[nn][bc]);
            bl[t] = *reinterpret_cast<const bf16x8*>(&Bl[nn][bc]);
        }
#pragma unroll
        for (int i = 0; i < 4; i++)
#pragma unroll
            for (int j = 0; j < 4; j++) {
                acc[i][j] = __builtin_amdgcn_mfma_f32_16x16x32_bf16(ah[i], bh[j], acc[i][j], 0, 0, 0);
                acc[i][j] = __builtin_amdgcn_mfma_f32_16x16x32_bf16(ah[i], bl[j], acc[i][j], 0, 0, 0);
                acc[i][j] = __builtin_amdgcn_mfma_f32_16x16x32_bf16(al[i], bh[j], acc[i][j], 0, 0, 0);
            }
    }

    // ---- epilogue ----
#pragma unroll
    for (int i = 0; i < 4; i++) {
        int rbase = m0 + wm + i * 16 + (lane >> 4) * 4;
#pragma unroll
        for (int q = 0; q < 4; q++) {
            int r = rbase + q;
            if (r < M) {
#pragma unroll
                for (int j = 0; j < 4; j++) {
                    int cidx = wn + j * 16 + (lane & 15);
                    float v = acc[i][j][q];
                    if (OUT_BR) v = fmaxf(v + out_bias[cidx], 0.f);
                    if (OUT_PLANES) {
                        ushort hi = bf16_rne(v);
                        float fhi = __uint_as_float((unsigned int)hi << 16);
                        Chp[(size_t)r * 128 + cidx] = hi;
                        Clp[(size_t)r * 128 + cidx] = bf16_rne(v - fhi);
                    } else {
                        C[(size_t)r * 128 + cidx] = v;
                    }
                }
            }
        }
    }
}

// ---------------- logits + softmax ----------------
__global__ __launch_bounds__(256) void logits_kernel(
    const float* __restrict__ a, const float* __restrict__ Wl2,
    const float* __restrict__ bl2, float* __restrict__ out, int M)
{
    __shared__ float sW2[128 * 32];
    const int tid = threadIdx.x;
    for (int i = tid * 4; i < 128 * 32; i += 256 * 4)
        *reinterpret_cast<float4*>(&sW2[i]) = *reinterpret_cast<const float4*>(&Wl2[i]);
    __syncthreads();

    const int lane = tid & 63;
    const int half = lane >> 5;
    const int o = lane & 31;
    const int hw = tid >> 5;
    const float lb = bl2[o];
    const int nhw = gridDim.x * 8;

    for (int n = blockIdx.x * 8 + hw; n < M; n += nhw) {
        float4 af = *reinterpret_cast<const float4*>(&a[(size_t)n * 128 + o * 4]);
        float p = 0.f;
#pragma unroll
        for (int c = 0; c < 32; c++) {
            int srcl = (half << 5) + c;
            float v0 = __shfl(af.x, srcl);
            float v1 = __shfl(af.y, srcl);
            float v2 = __shfl(af.z, srcl);
            float v3 = __shfl(af.w, srcl);
            int k = c * 4;
            p = fmaf(v0, sW2[(k + 0) * 32 + o], p);
            p = fmaf(v1, sW2[(k + 1) * 32 + o], p);
            p = fmaf(v2, sW2[(k + 2) * 32 + o], p);
            p = fmaf(v3, sW2[(k + 3) * 32 + o], p);
        }
        float l = p + lb;
        float m = l;
#pragma unroll
        for (int s = 16; s >= 1; s >>= 1) m = fmaxf(m, __shfl_xor(m, s));
        float e = __expf(l - m);
        float ssum = e;
#pragma unroll
        for (int s = 16; s >= 1; s >>= 1) ssum += __shfl_xor(ssum, s);
        out[(size_t)n * 32 + o] = e / ssum;
    }
}

// ---------------------------------------------------------------------------
extern "C" void kernel_launch(void* const* d_in, const int* in_sizes, int n_in,
                              void* d_out, int out_size, void* d_ws, size_t ws_size,
                              hipStream_t stream) {
    const float* x   = (const float*)d_in[0];
    const int*   ei  = (const int*)d_in[1];
    const float* ew  = (const float*)d_in[2];
    const float* Wp  = (const float*)d_in[3];
    const float* bp  = (const float*)d_in[4];
    const float* W1  = (const float*)d_in[5];
    const float* b1  = (const float*)d_in[6];
    const float* W2  = (const float*)d_in[7];
    const float* b2  = (const float*)d_in[8];
    const float* Wl1 = (const float*)d_in[9];
    const float* bl1 = (const float*)d_in[10];
    const float* Wl2 = (const float*)d_in[11];
    const float* bl2 = (const float*)d_in[12];
    float* out = (float*)d_out;

    const int M = in_sizes[0] / 256;   // 100000 nodes
    const int E = in_sizes[2];         // 1600000 edges
    const int* srcp = ei;
    const int* dstp = ei + E;

    // ---- workspace layout ----
    char* ws = (char*)d_ws;
    size_t off = 0;
    auto alloc = [&](size_t bytes) { void* p = ws + off; off = (off + bytes + 255) & ~(size_t)255; return p; };
    unsigned long long* packed = (unsigned long long*)alloc((size_t)M * 8);
    float*  dinv   = (float*) alloc((size_t)M * 4);
    int*    rowptr = (int*)   alloc((size_t)(M + 1) * 4);
    int*    bsum   = (int*)   alloc((size_t)4096 * 4);
    int2*   pairs  = (int2*)  alloc((size_t)E * 8);
    ushort* PAh    = (ushort*)alloc((size_t)M * 128 * 2);
    ushort* PAl    = (ushort*)alloc((size_t)M * 128 * 2);
    float*  F      = (float*) alloc((size_t)M * 128 * 4);
    ushort* WPh    = (ushort*)alloc((size_t)256 * 128 * 2);
    ushort* WPl    = (ushort*)alloc((size_t)256 * 128 * 2);
    ushort* W1h    = (ushort*)alloc((size_t)128 * 128 * 2);
    ushort* W1l    = (ushort*)alloc((size_t)128 * 128 * 2);
    ushort* W2h    = (ushort*)alloc((size_t)128 * 128 * 2);
    ushort* W2l    = (ushort*)alloc((size_t)128 * 128 * 2);
    ushort* WL1h   = (ushort*)alloc((size_t)128 * 128 * 2);
    ushort* WL1l   = (ushort*)alloc((size_t)128 * 128 * 2);

    int* rank = (int*)F;   // rank is dead before F's first write (GEMM-W1)

    const int ntiles = (M + 2047) / 2048;

    // ---- CSR build ----
    hipMemsetAsync(packed, 0, (size_t)M * 8, stream);
    deg_cnt_kernel<<<(E + 255) / 256, 256, 0, stream>>>(dstp, ew, packed, rank, E);
    dinv_kernel<<<(M + 255) / 256, 256, 0, stream>>>(packed, dinv, M);
    scan_reduce<<<ntiles, 256, 0, stream>>>(packed, bsum, M);
    scan_bsum<<<1, 64, 0, stream>>>(bsum, rowptr + M, ntiles);
    scan_down<<<ntiles, 256, 0, stream>>>(packed, bsum, rowptr, M);
    reorder_kernel<<<(E + 255) / 256, 256, 0, stream>>>(srcp, dstp, ew, dinv, rowptr, rank, pairs, E);

    // ---- weight pre-split (transposed planes) ----
    split_w_kernel<<<128, 256, 0, stream>>>(Wp, WPh, WPl, 256 * 128, 256);
    split_w_kernel<<<64, 256, 0, stream>>>(W1, W1h, W1l, 128 * 128, 128);
    split_w_kernel<<<64, 256, 0, stream>>>(W2, W2h, W2l, 128 * 128, 128);
    split_w_kernel<<<64, 256, 0, stream>>>(Wl1, WL1h, WL1l, 128 * 128, 128);

    const int gblocks = (M + 127) / 128;
    const int hblocks = (int)(((size_t)M * 32 + 255) / 256);

    // proj: PA = split(relu(x @ Wp + bp))
    gemm_mfma<256, false, true, true><<<gblocks, 256, 0, stream>>>(
        x, nullptr, nullptr, WPh, WPl, bp, nullptr, PAh, PAl, M);

    // GCN layer 1: F = PA @ W1 ; PA = split(relu(AGG(F) + b1))
    gemm_mfma<128, true, false, false><<<gblocks, 256, 0, stream>>>(
        nullptr, PAh, PAl, W1h, W1l, nullptr, F, nullptr, nullptr, M);
    gather_kernel<<<hblocks, 256, 0, stream>>>(rowptr, pairs, dinv, F, b1, PAh, PAl, M);

    // GCN layer 2: F = PA @ W2 ; PA = split(relu(AGG(F) + b2))
    gemm_mfma<128, true, false, false><<<gblocks, 256, 0, stream>>>(
        nullptr, PAh, PAl, W2h, W2l, nullptr, F, nullptr, nullptr, M);
    gather_kernel<<<hblocks, 256, 0, stream>>>(rowptr, pairs, dinv, F, b2, PAh, PAl, M);

    // head: F = relu(PA @ Wl1 + bl1); out = softmax(F @ Wl2 + bl2)
    gemm_mfma<128, true, true, false><<<gblocks, 256, 0, stream>>>(
        nullptr, PAh, PAl, WL1h, WL1l, bl1, F, nullptr, nullptr, M);
    logits_kernel<<<1024, 256, 0, stream>>>(F, Wl2, bl2, out, M);
}

// Round 8
// 732.670 us; speedup vs baseline: 8.2046x; 1.0228x over previous
//
#include <hip/hip_runtime.h>

// ---------------------------------------------------------------------------
// GCN forward. Round 7: fix R6's fused-head LDS corruption.
//  head_kernel: stage-1 split-bf16 MFMA in a 40KB pool ([128][40] tiles);
//  then per 64-row half: t written as fp32 into pool reinterpreted as
//  T[64][132] (no overflow), logits from fp32 T x fp32 sW2 (+softmax).
//  deg_cnt stays u32 single-atomic (cnt bits 25-31, deg 2^-19 fixed point).
// ---------------------------------------------------------------------------

typedef __attribute__((ext_vector_type(8))) short bf16x8;
typedef __attribute__((ext_vector_type(4))) short bf16x4;
typedef __attribute__((ext_vector_type(4))) float f32x4;

__device__ __forceinline__ ushort bf16_rne(float x) {
    unsigned int u = __float_as_uint(x);
    return (ushort)((u + 0x7FFFu + ((u >> 16) & 1u)) >> 16);
}

// LDS column swizzle: XOR k bits 3..4 with row bits 1..2 (8-block granular).
__device__ __forceinline__ int swz(int row, int k) {
    return k ^ (((row >> 1) & 3) << 3);
}

// ---------------- deg+cnt in one u32 atomic; rank = prior count ----------------
__global__ void deg_cnt_kernel(const int* __restrict__ dst, const float* __restrict__ ew,
                               unsigned int* __restrict__ packed,
                               int* __restrict__ rank, int E) {
    int e = blockIdx.x * blockDim.x + threadIdx.x;
    if (e < E) {
        int d = dst[e];
        unsigned int fx = __float2uint_rn(ew[e] * 524288.0f);   // 2^19
        unsigned int old = atomicAdd(&packed[d], (1u << 25) | fx);
        rank[e] = (int)(old >> 25);
    }
}

__global__ void dinv_kernel(const unsigned int* __restrict__ packed,
                            float* __restrict__ dinv, int N) {
    int i = blockIdx.x * blockDim.x + threadIdx.x;
    if (i < N) {
        float deg = (float)(packed[i] & 0x1FFFFFFu) * (1.0f / 524288.0f);
        dinv[i] = 1.0f / sqrtf(deg + 1.0f);
    }
}

// ---------------- hierarchical exclusive scan over cnt (= packed>>25) ----------------
__global__ __launch_bounds__(256) void scan_reduce(const unsigned int* __restrict__ packed,
                                                   int* __restrict__ bsum, int M) {
    __shared__ int wsum[4];
    const int t = threadIdx.x;
    const int base = blockIdx.x * 2048 + t * 8;
    int s = 0;
#pragma unroll
    for (int j = 0; j < 8; j++) {
        int i = base + j;
        if (i < M) s += (int)(packed[i] >> 25);
    }
#pragma unroll
    for (int off = 1; off < 64; off <<= 1) s += __shfl_xor(s, off);
    if ((t & 63) == 0) wsum[t >> 6] = s;
    __syncthreads();
    if (t == 0) bsum[blockIdx.x] = wsum[0] + wsum[1] + wsum[2] + wsum[3];
}

__global__ void scan_bsum(int* __restrict__ bsum, int* __restrict__ rowptr_last, int nb) {
    const int lane = threadIdx.x;
    const int chunk = (nb + 63) / 64;
    const int b0 = lane * chunk;
    const int b1 = min(b0 + chunk, nb);
    int s = 0;
    for (int i = b0; i < b1; i++) s += bsum[i];
    int inc = s;
#pragma unroll
    for (int off = 1; off < 64; off <<= 1) {
        int u = __shfl_up(inc, off);
        if (lane >= off) inc += u;
    }
    int run = inc - s;
    for (int i = b0; i < b1; i++) {
        int v = bsum[i];
        bsum[i] = run;
        run += v;
    }
    if (lane == 63) *rowptr_last = inc;
}

__global__ __launch_bounds__(256) void scan_down(const unsigned int* __restrict__ packed,
                                                 const int* __restrict__ bsum,
                                                 int* __restrict__ rowptr, int M) {
    __shared__ int wpre[4];
    const int t = threadIdx.x;
    const int lane = t & 63;
    const int w = t >> 6;
    const int base = blockIdx.x * 2048 + t * 8;
    int c[8];
    int s = 0;
#pragma unroll
    for (int j = 0; j < 8; j++) {
        int i = base + j;
        c[j] = (i < M) ? (int)(packed[i] >> 25) : 0;
        s += c[j];
    }
    int inc = s;
#pragma unroll
    for (int off = 1; off < 64; off <<= 1) {
        int u = __shfl_up(inc, off);
        if (lane >= off) inc += u;
    }
    if (lane == 63) wpre[w] = inc;
    __syncthreads();
    int woff = 0;
#pragma unroll
    for (int i = 0; i < 4; i++)
        if (i < w) woff += wpre[i];
    int run = bsum[blockIdx.x] + woff + (inc - s);
#pragma unroll
    for (int j = 0; j < 8; j++) {
        int i = base + j;
        if (i < M) {
            rowptr[i] = run;
            run += c[j];
        }
    }
}

// ---------------- reorder (atomic-free): pairs[rowptr[d]+rank[e]] ----------------
__global__ void reorder_kernel(const int* __restrict__ src, const int* __restrict__ dst,
                               const float* __restrict__ ew, const float* __restrict__ dinv,
                               const int* __restrict__ rowptr, const int* __restrict__ rank,
                               int2* __restrict__ pairs, int E) {
    int e = blockIdx.x * blockDim.x + threadIdx.x;
    if (e < E) {
        int s = src[e], d = dst[e];
        float w = dinv[s] * ew[e] * dinv[d];
        pairs[rowptr[d] + rank[e]] = make_int2(s, __float_as_int(w));
    }
}

// ---------------- weight pre-split: W[K][N] -> planes [n][K] hi/lo ----------------
template<int N>
__global__ void split_w_kernel(const float* __restrict__ W, ushort* __restrict__ ph,
                               ushort* __restrict__ pl, int total, int Kdim) {
    int id = blockIdx.x * blockDim.x + threadIdx.x;
    if (id < total) {
        int k = id / N;
        int n = id % N;
        float x = W[id];
        ushort hi = bf16_rne(x);
        float fhi = __uint_as_float((unsigned int)hi << 16);
        ph[n * Kdim + k] = hi;
        pl[n * Kdim + k] = bf16_rne(x - fhi);
    }
}

// ---------------- CSR gather + bias/relu + hi/lo plane epilogue ----------------
__global__ __launch_bounds__(256) void gather_kernel(
    const int* __restrict__ rowptr, const int2* __restrict__ pairs,
    const float* __restrict__ dinv, const float* __restrict__ hW,
    const float* __restrict__ bias, ushort* __restrict__ ph,
    ushort* __restrict__ pl, int M)
{
    int gid = blockIdx.x * blockDim.x + threadIdx.x;
    int n = gid >> 5;
    int c = (gid & 31) * 4;
    if (n >= M) return;
    int beg = rowptr[n], end = rowptr[n + 1];
    float di = dinv[n];
    float s = di * di;
    float4 v = *reinterpret_cast<const float4*>(&hW[(size_t)n * 128 + c]);
    float4 acc0 = make_float4(s * v.x, s * v.y, s * v.z, s * v.w);
    float4 acc1 = make_float4(0.f, 0.f, 0.f, 0.f);

    int e = beg;
    for (; e + 4 <= end; e += 4) {
        int2 p0 = pairs[e + 0];
        int2 p1 = pairs[e + 1];
        int2 p2 = pairs[e + 2];
        int2 p3 = pairs[e + 3];
        float4 h0 = *reinterpret_cast<const float4*>(&hW[(size_t)p0.x * 128 + c]);
        float4 h1 = *reinterpret_cast<const float4*>(&hW[(size_t)p1.x * 128 + c]);
        float4 h2 = *reinterpret_cast<const float4*>(&hW[(size_t)p2.x * 128 + c]);
        float4 h3 = *reinterpret_cast<const float4*>(&hW[(size_t)p3.x * 128 + c]);
        float w0 = __int_as_float(p0.y), w1 = __int_as_float(p1.y);
        float w2 = __int_as_float(p2.y), w3 = __int_as_float(p3.y);
        acc0.x = fmaf(w0, h0.x, acc0.x); acc0.y = fmaf(w0, h0.y, acc0.y);
        acc0.z = fmaf(w0, h0.z, acc0.z); acc0.w = fmaf(w0, h0.w, acc0.w);
        acc1.x = fmaf(w1, h1.x, acc1.x); acc1.y = fmaf(w1, h1.y, acc1.y);
        acc1.z = fmaf(w1, h1.z, acc1.z); acc1.w = fmaf(w1, h1.w, acc1.w);
        acc0.x = fmaf(w2, h2.x, acc0.x); acc0.y = fmaf(w2, h2.y, acc0.y);
        acc0.z = fmaf(w2, h2.z, acc0.z); acc0.w = fmaf(w2, h2.w, acc0.w);
        acc1.x = fmaf(w3, h3.x, acc1.x); acc1.y = fmaf(w3, h3.y, acc1.y);
        acc1.z = fmaf(w3, h3.z, acc1.z); acc1.w = fmaf(w3, h3.w, acc1.w);
    }
    for (; e < end; e++) {
        int2 p = pairs[e];
        float w = __int_as_float(p.y);
        float4 h = *reinterpret_cast<const float4*>(&hW[(size_t)p.x * 128 + c]);
        acc0.x = fmaf(w, h.x, acc0.x);
        acc0.y = fmaf(w, h.y, acc0.y);
        acc0.z = fmaf(w, h.z, acc0.z);
        acc0.w = fmaf(w, h.w, acc0.w);
    }
    float4 b = *reinterpret_cast<const float4*>(&bias[c]);
    float tt[4];
    tt[0] = fmaxf(acc0.x + acc1.x + b.x, 0.f);
    tt[1] = fmaxf(acc0.y + acc1.y + b.y, 0.f);
    tt[2] = fmaxf(acc0.z + acc1.z + b.z, 0.f);
    tt[3] = fmaxf(acc0.w + acc1.w + b.w, 0.f);
    ushort h4[4], l4[4];
#pragma unroll
    for (int j = 0; j < 4; j++) {
        ushort hi = bf16_rne(tt[j]);
        float fhi = __uint_as_float((unsigned int)hi << 16);
        h4[j] = hi;
        l4[j] = bf16_rne(tt[j] - fhi);
    }
    *reinterpret_cast<bf16x4*>(&ph[(size_t)n * 128 + c]) = *reinterpret_cast<bf16x4*>(h4);
    *reinterpret_cast<bf16x4*>(&pl[(size_t)n * 128 + c]) = *reinterpret_cast<bf16x4*>(l4);
}

// ---------------- split-bf16 MFMA GEMM ----------------
template<int K, bool A_PRE, bool OUT_BR, bool OUT_PLANES>
__global__ __launch_bounds__(256) void gemm_mfma(
    const float* __restrict__ A,
    const ushort* __restrict__ Ahp, const ushort* __restrict__ Alp,
    const ushort* __restrict__ Bhp, const ushort* __restrict__ Blp,
    const float* __restrict__ out_bias,
    float* __restrict__ C, ushort* __restrict__ Chp, ushort* __restrict__ Clp,
    int M)
{
    __shared__ ushort Ah[128][40], Al[128][40], Bh[128][40], Bl[128][40];

    const int tid = threadIdx.x;
    const int lane = tid & 63;
    const int wave = tid >> 6;
    const int wm = (wave >> 1) * 64;
    const int wn = (wave & 1) * 64;
    const int m0 = blockIdx.x * 128;

    f32x4 acc[4][4] = {};

    const int sr = tid >> 1;
    const int sk = (tid & 1) * 16;
    const int fm = lane & 15;
    const int fk = (lane >> 4) * 8;

    for (int k0 = 0; k0 < K; k0 += 32) {
        __syncthreads();
        if (A_PRE) {
            const bool valid = (m0 + sr) < M;
            bf16x8 zero = {};
            bf16x8 h0 = zero, h1 = zero, l0 = zero, l1 = zero;
            if (valid) {
                const ushort* ph = &Ahp[(size_t)(m0 + sr) * K + k0 + sk];
                const ushort* pl = &Alp[(size_t)(m0 + sr) * K + k0 + sk];
                h0 = *reinterpret_cast<const bf16x8*>(ph);
                h1 = *reinterpret_cast<const bf16x8*>(ph + 8);
                l0 = *reinterpret_cast<const bf16x8*>(pl);
                l1 = *reinterpret_cast<const bf16x8*>(pl + 8);
            }
            *reinterpret_cast<bf16x8*>(&Ah[sr][swz(sr, sk)]) = h0;
            *reinterpret_cast<bf16x8*>(&Ah[sr][swz(sr, sk + 8)]) = h1;
            *reinterpret_cast<bf16x8*>(&Al[sr][swz(sr, sk)]) = l0;
            *reinterpret_cast<bf16x8*>(&Al[sr][swz(sr, sk + 8)]) = l1;
        } else {
            const bool valid = (m0 + sr) < M;
            const float* srcp = &A[(size_t)(m0 + sr) * K + k0 + sk];
#pragma unroll
            for (int q = 0; q < 2; q++) {
                float vv[8];
                if (valid) {
                    *reinterpret_cast<float4*>(&vv[0]) = *reinterpret_cast<const float4*>(srcp + q * 8);
                    *reinterpret_cast<float4*>(&vv[4]) = *reinterpret_cast<const float4*>(srcp + q * 8 + 4);
                } else {
#pragma unroll
                    for (int j = 0; j < 8; j++) vv[j] = 0.f;
                }
                ushort hh[8], ll[8];
#pragma unroll
                for (int j = 0; j < 8; j++) {
                    ushort hi = bf16_rne(vv[j]);
                    float fhi = __uint_as_float((unsigned int)hi << 16);
                    hh[j] = hi;
                    ll[j] = bf16_rne(vv[j] - fhi);
                }
                int col = swz(sr, sk + q * 8);
                *reinterpret_cast<bf16x8*>(&Ah[sr][col]) = *reinterpret_cast<bf16x8*>(hh);
                *reinterpret_cast<bf16x8*>(&Al[sr][col]) = *reinterpret_cast<bf16x8*>(ll);
            }
        }
        {
            const ushort* ph = &Bhp[(size_t)sr * K + k0 + sk];
            const ushort* pl = &Blp[(size_t)sr * K + k0 + sk];
            *reinterpret_cast<bf16x8*>(&Bh[sr][swz(sr, sk)]) = *reinterpret_cast<const bf16x8*>(ph);
            *reinterpret_cast<bf16x8*>(&Bh[sr][swz(sr, sk + 8)]) = *reinterpret_cast<const bf16x8*>(ph + 8);
            *reinterpret_cast<bf16x8*>(&Bl[sr][swz(sr, sk)]) = *reinterpret_cast<const bf16x8*>(pl);
            *reinterpret_cast<bf16x8*>(&Bl[sr][swz(sr, sk + 8)]) = *reinterpret_cast<const bf16x8*>(pl + 8);
        }
        __syncthreads();

        bf16x8 ah[4], al[4], bh[4], bl[4];
#pragma unroll
        for (int t = 0; t < 4; t++) {
            int am = wm + t * 16 + fm;
            int ac = swz(am, fk);
            ah[t] = *reinterpret_cast<const bf16x8*>(&Ah[am][ac]);
            al[t] = *reinterpret_cast<const bf16x8*>(&Al[am][ac]);
            int nn = wn + t * 16 + fm;
            int bc = swz(nn, fk);
            bh[t] = *reinterpret_cast<const bf16x8*>(&Bh[nn][bc]);
            bl[t] = *reinterpret_cast<const bf16x8*>(&Bl[nn][bc]);
        }
#pragma unroll
        for (int i = 0; i < 4; i++)
#pragma unroll
            for (int j = 0; j < 4; j++) {
                acc[i][j] = __builtin_amdgcn_mfma_f32_16x16x32_bf16(ah[i], bh[j], acc[i][j], 0, 0, 0);
                acc[i][j] = __builtin_amdgcn_mfma_f32_16x16x32_bf16(ah[i], bl[j], acc[i][j], 0, 0, 0);
                acc[i][j] = __builtin_amdgcn_mfma_f32_16x16x32_bf16(al[i], bh[j], acc[i][j], 0, 0, 0);
            }
    }

#pragma unroll
    for (int i = 0; i < 4; i++) {
        int rbase = m0 + wm + i * 16 + (lane >> 4) * 4;
#pragma unroll
        for (int q = 0; q < 4; q++) {
            int r = rbase + q;
            if (r < M) {
#pragma unroll
                for (int j = 0; j < 4; j++) {
                    int cidx = wn + j * 16 + (lane & 15);
                    float v = acc[i][j][q];
                    if (OUT_BR) v = fmaxf(v + out_bias[cidx], 0.f);
                    if (OUT_PLANES) {
                        ushort hi = bf16_rne(v);
                        float fhi = __uint_as_float((unsigned int)hi << 16);
                        Chp[(size_t)r * 128 + cidx] = hi;
                        Clp[(size_t)r * 128 + cidx] = bf16_rne(v - fhi);
                    } else {
                        C[(size_t)r * 128 + cidx] = v;
                    }
                }
            }
        }
    }
}

// ---------------- fused head: t = relu(PA@Wl1+bl1); out = softmax(t@Wl2+bl2) ----------------
// Stage 1: split-bf16 MFMA (pool as 4x [128][40] tiles). Then two 64-row
// halves: t written fp32 into pool as T[64][132]; logits fp32 from T x sW2;
// 32-lane shfl softmax.
__global__ __launch_bounds__(256) void head_kernel(
    const ushort* __restrict__ Ahp, const ushort* __restrict__ Alp,
    const ushort* __restrict__ B1h, const ushort* __restrict__ B1l,
    const float* __restrict__ Wl2, const float* __restrict__ bl1,
    const float* __restrict__ bl2, float* __restrict__ out, int M)
{
    __shared__ ushort pool[20480];     // 40 KB
    __shared__ float sW2[128 * 32];    // 16 KB

    ushort* Ah = pool;                 // [128][40]
    ushort* Al = pool + 5120;
    ushort* Bh = pool + 10240;
    ushort* Bl = pool + 15360;

    const int tid = threadIdx.x;
    const int lane = tid & 63;
    const int wave = tid >> 6;
    const int wm = (wave >> 1) * 64;
    const int wn = (wave & 1) * 64;
    const int m0 = blockIdx.x * 128;

    // stage Wl2 fp32 (row-major [k][o], exactly what logits needs)
#pragma unroll
    for (int i = 0; i < 4; i++) {
        int idx = tid * 4 + i * 1024;
        *reinterpret_cast<float4*>(&sW2[idx]) = *reinterpret_cast<const float4*>(&Wl2[idx]);
    }

    f32x4 acc[4][4] = {};

    const int sr = tid >> 1;
    const int sk = (tid & 1) * 16;
    const int fm = lane & 15;
    const int fq = lane >> 4;
    const int fk = fq * 8;

    // ---- stage 1: K=128 split-bf16 GEMM (PA @ Wl1) ----
    for (int k0 = 0; k0 < 128; k0 += 32) {
        __syncthreads();
        {
            const bool valid = (m0 + sr) < M;
            bf16x8 zero = {};
            bf16x8 h0 = zero, h1 = zero, l0 = zero, l1 = zero;
            if (valid) {
                const ushort* ph = &Ahp[(size_t)(m0 + sr) * 128 + k0 + sk];
                const ushort* pl = &Alp[(size_t)(m0 + sr) * 128 + k0 + sk];
                h0 = *reinterpret_cast<const bf16x8*>(ph);
                h1 = *reinterpret_cast<const bf16x8*>(ph + 8);
                l0 = *reinterpret_cast<const bf16x8*>(pl);
                l1 = *reinterpret_cast<const bf16x8*>(pl + 8);
            }
            *reinterpret_cast<bf16x8*>(&Ah[sr * 40 + swz(sr, sk)]) = h0;
            *reinterpret_cast<bf16x8*>(&Ah[sr * 40 + swz(sr, sk + 8)]) = h1;
            *reinterpret_cast<bf16x8*>(&Al[sr * 40 + swz(sr, sk)]) = l0;
            *reinterpret_cast<bf16x8*>(&Al[sr * 40 + swz(sr, sk + 8)]) = l1;
            const ushort* qh = &B1h[(size_t)sr * 128 + k0 + sk];
            const ushort* ql = &B1l[(size_t)sr * 128 + k0 + sk];
            *reinterpret_cast<bf16x8*>(&Bh[sr * 40 + swz(sr, sk)]) = *reinterpret_cast<const bf16x8*>(qh);
            *reinterpret_cast<bf16x8*>(&Bh[sr * 40 + swz(sr, sk + 8)]) = *reinterpret_cast<const bf16x8*>(qh + 8);
            *reinterpret_cast<bf16x8*>(&Bl[sr * 40 + swz(sr, sk)]) = *reinterpret_cast<const bf16x8*>(ql);
            *reinterpret_cast<bf16x8*>(&Bl[sr * 40 + swz(sr, sk + 8)]) = *reinterpret_cast<const bf16x8*>(ql + 8);
        }
        __syncthreads();

        bf16x8 ah[4], al[4], bh[4], bl[4];
#pragma unroll
        for (int t = 0; t < 4; t++) {
            int am = wm + t * 16 + fm;
            int ac = swz(am, fk);
            ah[t] = *reinterpret_cast<const bf16x8*>(&Ah[am * 40 + ac]);
            al[t] = *reinterpret_cast<const bf16x8*>(&Al[am * 40 + ac]);
            int nn = wn + t * 16 + fm;
            int bc = swz(nn, fk);
            bh[t] = *reinterpret_cast<const bf16x8*>(&Bh[nn * 40 + bc]);
            bl[t] = *reinterpret_cast<const bf16x8*>(&Bl[nn * 40 + bc]);
        }
#pragma unroll
        for (int i = 0; i < 4; i++)
#pragma unroll
            for (int j = 0; j < 4; j++) {
                acc[i][j] = __builtin_amdgcn_mfma_f32_16x16x32_bf16(ah[i], bh[j], acc[i][j], 0, 0, 0);
                acc[i][j] = __builtin_amdgcn_mfma_f32_16x16x32_bf16(ah[i], bl[j], acc[i][j], 0, 0, 0);
                acc[i][j] = __builtin_amdgcn_mfma_f32_16x16x32_bf16(al[i], bh[j], acc[i][j], 0, 0, 0);
            }
    }
    __syncthreads();   // all stage-1 LDS reads done

    // ---- two 64-row halves: T[64][132] fp32 in pool, then logits+softmax ----
    float* T = reinterpret_cast<float*>(pool);   // 64*132 floats = 33.8 KB
    const int o = lane & 31;
    const int hw2 = tid >> 5;                    // half-wave id 0..7
    const float lb = bl2[o];

    for (int h = 0; h < 2; h++) {
        if ((wm >> 6) == h) {
            // this wave owns rows h*64..h*64+63, cols wn..wn+63
#pragma unroll
            for (int i = 0; i < 4; i++) {
                int rl = i * 16 + fq * 4;        // local row base 0..63
#pragma unroll
                for (int q = 0; q < 4; q++) {
#pragma unroll
                    for (int j = 0; j < 4; j++) {
                        int col = wn + j * 16 + fm;
                        T[(rl + q) * 132 + col] = fmaxf(acc[i][j][q] + bl1[col], 0.f);
                    }
                }
            }
        }
        __syncthreads();

        // logits + softmax for rows h*64 .. h*64+63 (8 rows per half-wave)
        for (int rr = hw2; rr < 64; rr += 8) {
            const float* Trow = &T[rr * 132];
            float p = 0.f;
#pragma unroll
            for (int c = 0; c < 128; c += 4) {
                float4 tv = *reinterpret_cast<const float4*>(&Trow[c]);
                p = fmaf(tv.x, sW2[(c + 0) * 32 + o], p);
                p = fmaf(tv.y, sW2[(c + 1) * 32 + o], p);
                p = fmaf(tv.z, sW2[(c + 2) * 32 + o], p);
                p = fmaf(tv.w, sW2[(c + 3) * 32 + o], p);
            }
            p += lb;
            float mx = p;
#pragma unroll
            for (int s = 16; s >= 1; s >>= 1) mx = fmaxf(mx, __shfl_xor(mx, s));
            float e = __expf(p - mx);
            float ss = e;
#pragma unroll
            for (int s = 16; s >= 1; s >>= 1) ss += __shfl_xor(ss, s);
            int r = m0 + h * 64 + rr;
            if (r < M) out[(size_t)r * 32 + o] = e / ss;
        }
        __syncthreads();
    }
}

// ---------------------------------------------------------------------------
extern "C" void kernel_launch(void* const* d_in, const int* in_sizes, int n_in,
                              void* d_out, int out_size, void* d_ws, size_t ws_size,
                              hipStream_t stream) {
    const float* x   = (const float*)d_in[0];
    const int*   ei  = (const int*)d_in[1];
    const float* ew  = (const float*)d_in[2];
    const float* Wp  = (const float*)d_in[3];
    const float* bp  = (const float*)d_in[4];
    const float* W1  = (const float*)d_in[5];
    const float* b1  = (const float*)d_in[6];
    const float* W2  = (const float*)d_in[7];
    const float* b2  = (const float*)d_in[8];
    const float* Wl1 = (const float*)d_in[9];
    const float* bl1 = (const float*)d_in[10];
    const float* Wl2 = (const float*)d_in[11];
    const float* bl2 = (const float*)d_in[12];
    float* out = (float*)d_out;

    const int M = in_sizes[0] / 256;   // 100000 nodes
    const int E = in_sizes[2];         // 1600000 edges
    const int* srcp = ei;
    const int* dstp = ei + E;

    // ---- workspace layout ----
    char* ws = (char*)d_ws;
    size_t off = 0;
    auto alloc = [&](size_t bytes) { void* p = ws + off; off = (off + bytes + 255) & ~(size_t)255; return p; };
    unsigned int* packed = (unsigned int*)alloc((size_t)M * 4);
    float*  dinv   = (float*) alloc((size_t)M * 4);
    int*    rowptr = (int*)   alloc((size_t)(M + 1) * 4);
    int*    bsum   = (int*)   alloc((size_t)4096 * 4);
    int2*   pairs  = (int2*)  alloc((size_t)E * 8);
    ushort* PAh    = (ushort*)alloc((size_t)M * 128 * 2);
    ushort* PAl    = (ushort*)alloc((size_t)M * 128 * 2);
    float*  F      = (float*) alloc((size_t)M * 128 * 4);
    ushort* WPh    = (ushort*)alloc((size_t)256 * 128 * 2);
    ushort* WPl    = (ushort*)alloc((size_t)256 * 128 * 2);
    ushort* W1h    = (ushort*)alloc((size_t)128 * 128 * 2);
    ushort* W1l    = (ushort*)alloc((size_t)128 * 128 * 2);
    ushort* W2h    = (ushort*)alloc((size_t)128 * 128 * 2);
    ushort* W2l    = (ushort*)alloc((size_t)128 * 128 * 2);
    ushort* WL1h   = (ushort*)alloc((size_t)128 * 128 * 2);
    ushort* WL1l   = (ushort*)alloc((size_t)128 * 128 * 2);

    int* rank = (int*)F;   // rank is dead before F's first write (GEMM-W1)

    const int ntiles = (M + 2047) / 2048;

    // ---- CSR build ----
    hipMemsetAsync(packed, 0, (size_t)M * 4, stream);
    deg_cnt_kernel<<<(E + 255) / 256, 256, 0, stream>>>(dstp, ew, packed, rank, E);
    dinv_kernel<<<(M + 255) / 256, 256, 0, stream>>>(packed, dinv, M);
    scan_reduce<<<ntiles, 256, 0, stream>>>(packed, bsum, M);
    scan_bsum<<<1, 64, 0, stream>>>(bsum, rowptr + M, ntiles);
    scan_down<<<ntiles, 256, 0, stream>>>(packed, bsum, rowptr, M);
    reorder_kernel<<<(E + 255) / 256, 256, 0, stream>>>(srcp, dstp, ew, dinv, rowptr, rank, pairs, E);

    // ---- weight pre-split (transposed planes) ----
    split_w_kernel<128><<<128, 256, 0, stream>>>(Wp, WPh, WPl, 256 * 128, 256);
    split_w_kernel<128><<<64, 256, 0, stream>>>(W1, W1h, W1l, 128 * 128, 128);
    split_w_kernel<128><<<64, 256, 0, stream>>>(W2, W2h, W2l, 128 * 128, 128);
    split_w_kernel<128><<<64, 256, 0, stream>>>(Wl1, WL1h, WL1l, 128 * 128, 128);

    const int gblocks = (M + 127) / 128;
    const int hblocks = (int)(((size_t)M * 32 + 255) / 256);

    // proj: PA = split(relu(x @ Wp + bp))
    gemm_mfma<256, false, true, true><<<gblocks, 256, 0, stream>>>(
        x, nullptr, nullptr, WPh, WPl, bp, nullptr, PAh, PAl, M);

    // GCN layer 1: F = PA @ W1 ; PA = split(relu(AGG(F) + b1))
    gemm_mfma<128, true, false, false><<<gblocks, 256, 0, stream>>>(
        nullptr, PAh, PAl, W1h, W1l, nullptr, F, nullptr, nullptr, M);
    gather_kernel<<<hblocks, 256, 0, stream>>>(rowptr, pairs, dinv, F, b1, PAh, PAl, M);

    // GCN layer 2: F = PA @ W2 ; PA = split(relu(AGG(F) + b2))
    gemm_mfma<128, true, false, false><<<gblocks, 256, 0, stream>>>(
        nullptr, PAh, PAl, W2h, W2l, nullptr, F, nullptr, nullptr, M);
    gather_kernel<<<hblocks, 256, 0, stream>>>(rowptr, pairs, dinv, F, b2, PAh, PAl, M);

    // fused head: out = softmax(relu(PA@Wl1+bl1)@Wl2 + bl2)
    head_kernel<<<gblocks, 256, 0, stream>>>(
        PAh, PAl, WL1h, WL1l, Wl2, bl1, bl2, out, M);
}